// Round 1
// baseline (1729.699 us; speedup 1.0000x reference)
//
#include <hip/hip_runtime.h>
#include <cstdint>
#include <cstddef>

#define HID 128
#define OUTC 40

// ---------------- small utility kernels ----------------

__global__ void init_kernel(int* __restrict__ cnt, float* __restrict__ sim,
                            float* __restrict__ stats, int n) {
  int idx = blockIdx.x * blockDim.x + threadIdx.x;
  if (idx < n) { cnt[idx] = 0; sim[idx] = 1.0f; }  // sim starts at self-loop dot = 1
  if (idx < 1024) stats[idx] = 0.0f;
}

__global__ void rnorm_kernel(const float* __restrict__ alpha, float* __restrict__ rn, int n) {
  int g = (blockIdx.x * blockDim.x + threadIdx.x) >> 4;  // 16 lanes / node
  int lane = threadIdx.x & 15;
  if (g >= n) return;
  const float4 a = *(const float4*)(alpha + (size_t)g * 64 + lane * 4);
  float d = a.x * a.x + a.y * a.y + a.z * a.z + a.w * a.w;
  d += __shfl_xor(d, 1); d += __shfl_xor(d, 2);
  d += __shfl_xor(d, 4); d += __shfl_xor(d, 8);
  if (lane == 0) rn[g] = 1.0f / fmaxf(sqrtf(d), 1e-12f);
}

__global__ void count_kernel(const int* __restrict__ tgt, int* __restrict__ cnt, int e) {
  int idx = blockIdx.x * blockDim.x + threadIdx.x;
  if (idx < e) atomicAdd(cnt + tgt[idx], 1);
}

// ---------------- exclusive scan (3-kernel) ----------------

#define SCAN_T 256
#define SCAN_VPT 8
#define SCAN_ELEMS 2048

__global__ void scan1_kernel(const int* __restrict__ cnt, int* __restrict__ rowptr,
                             int* __restrict__ blksum, int n) {
  __shared__ int sh[SCAN_T];
  int t = threadIdx.x;
  int base = blockIdx.x * SCAN_ELEMS + t * SCAN_VPT;
  int v[SCAN_VPT];
  int s = 0;
#pragma unroll
  for (int i = 0; i < SCAN_VPT; ++i) {
    int idx = base + i;
    v[i] = (idx < n) ? cnt[idx] : 0;
    s += v[i];
  }
  sh[t] = s;
  __syncthreads();
  for (int d = 1; d < SCAN_T; d <<= 1) {
    int add = (t >= d) ? sh[t - d] : 0;
    __syncthreads();
    sh[t] += add;
    __syncthreads();
  }
  int p = sh[t] - s;  // exclusive offset of this thread within block
#pragma unroll
  for (int i = 0; i < SCAN_VPT; ++i) {
    int idx = base + i;
    if (idx < n) rowptr[idx] = p;
    p += v[i];
  }
  if (t == SCAN_T - 1) blksum[blockIdx.x] = sh[t];
}

__global__ void scan2_kernel(int* __restrict__ blk, int nb) {
  __shared__ int sh[SCAN_T];
  int t = threadIdx.x;
  int s = (t < nb) ? blk[t] : 0;
  sh[t] = s;
  __syncthreads();
  for (int d = 1; d < SCAN_T; d <<= 1) {
    int add = (t >= d) ? sh[t - d] : 0;
    __syncthreads();
    sh[t] += add;
    __syncthreads();
  }
  if (t < nb) blk[t] = sh[t] - s;  // exclusive
}

__global__ void scan3_kernel(int* __restrict__ rowptr, int* __restrict__ cursor,
                             const int* __restrict__ blkoff, int n, int etot) {
  int idx = blockIdx.x * blockDim.x + threadIdx.x;
  if (idx < n) {
    int r = rowptr[idx] + blkoff[idx / SCAN_ELEMS];
    rowptr[idx] = r;
    cursor[idx] = r;
  } else if (idx == n) {
    rowptr[n] = etot;
  }
}

__global__ void scatter_kernel(const int* __restrict__ src, const int* __restrict__ tgt,
                               int* __restrict__ cursor, int* __restrict__ csr, int e) {
  int idx = blockIdx.x * blockDim.x + threadIdx.x;
  if (idx >= e) return;
  int v = tgt[idx];
  int pos = atomicAdd(cursor + v, 1);
  csr[pos] = src[idx];
}

// ---------------- gate ----------------

__global__ void gate_edge_kernel(const float* __restrict__ alpha, const int* __restrict__ src,
                                 const int* __restrict__ tgt, const float* __restrict__ rn,
                                 float* __restrict__ sim, int e) {
  int g = (blockIdx.x * blockDim.x + threadIdx.x) >> 4;  // 16 lanes / edge
  int lane = threadIdx.x & 15;
  if (g >= e) return;
  int u = src[g], v = tgt[g];
  float4 a = *(const float4*)(alpha + (size_t)u * 64 + lane * 4);
  float4 b = *(const float4*)(alpha + (size_t)v * 64 + lane * 4);
  float d = a.x * b.x + a.y * b.y + a.z * b.z + a.w * b.w;
  d += __shfl_xor(d, 1); d += __shfl_xor(d, 2);
  d += __shfl_xor(d, 4); d += __shfl_xor(d, 8);
  if (lane == 0) atomicAdd(sim + v, d * rn[u] * rn[v]);
}

__global__ void gate_final_kernel(const float* __restrict__ sim, const int* __restrict__ cnt,
                                  const float* __restrict__ temp, float* __restrict__ out, int n) {
  int v = blockIdx.x * blockDim.x + threadIdx.x;
  if (v >= n) return;
  float m = sim[v] / (float)(cnt[v] + 1);   // +1 self-loop
  float t = temp[0];
  out[v] = 1.0f / (1.0f + expf(-t * m));
}

// ---------------- SAGE mean aggregation (pull, no atomics) ----------------

__global__ void aggregate_kernel(const float* __restrict__ h, const int* __restrict__ rowptr,
                                 const int* __restrict__ csr, float* __restrict__ out, int n) {
  int g = (blockIdx.x * blockDim.x + threadIdx.x) >> 5;  // 32 lanes / node
  int lane = threadIdx.x & 31;
  if (g >= n) return;
  int beg = rowptr[g], end = rowptr[g + 1];
  float4 acc = make_float4(0.f, 0.f, 0.f, 0.f);
  int j = beg;
  for (; j + 1 < end; j += 2) {
    int u0 = csr[j], u1 = csr[j + 1];
    float4 v0 = *(const float4*)(h + (size_t)u0 * HID + lane * 4);
    float4 v1 = *(const float4*)(h + (size_t)u1 * HID + lane * 4);
    acc.x += v0.x + v1.x; acc.y += v0.y + v1.y;
    acc.z += v0.z + v1.z; acc.w += v0.w + v1.w;
  }
  if (j < end) {
    int u = csr[j];
    float4 v0 = *(const float4*)(h + (size_t)u * HID + lane * 4);
    acc.x += v0.x; acc.y += v0.y; acc.z += v0.z; acc.w += v0.w;
  }
  float r = (end > beg) ? 1.0f / (float)(end - beg) : 0.f;
  acc.x *= r; acc.y *= r; acc.z *= r; acc.w *= r;
  *(float4*)(out + (size_t)g * HID + lane * 4) = acc;
}

// ---------------- fused linear: C = [relu?](A)@Wa^T (+ [relu?](B)@Wb^T) + bias ----------------
// BM=128 rows/block, BN cols (tile), BK=32. 256 threads: thread (ty=tid/16, tx=tid%16)
// computes rows ty*8+i (i<8) x cols tx+16j (j<BN/16). LDS transposed+padded, conflict-free.
// In-place C==A is safe: all global reads of a block's rows precede its writes.

template <int BN, bool HAS_B, bool IN_RELU>
__global__ __launch_bounds__(256) void lin_kernel(
    const float* A, int Ka, const float* B, int Kb,
    const float* __restrict__ Wa, const float* __restrict__ Wb, int WS,
    const float* __restrict__ bias, float* C, int M, int NC) {
  constexpr int BM = 128, BK = 32;
  constexpr int CPT = BN / 16;
  __shared__ float As[BK][BM + 4];   // [k][m], pad->132 (float4-aligned rows)
  __shared__ float Ws[BK][BN + 1];   // [k][c], pad odd
  const int tid = threadIdx.x;
  const int tx = tid & 15, ty = tid >> 4;
  const int mbase = blockIdx.x * BM;
  float acc[8][CPT];
#pragma unroll
  for (int i = 0; i < 8; ++i)
#pragma unroll
    for (int j = 0; j < CPT; ++j) acc[i][j] = 0.0f;

  const int nparts = HAS_B ? 2 : 1;
  for (int part = 0; part < nparts; ++part) {
    const float* Ap = (part == 0) ? A : B;
    const float* Wp = (part == 0) ? Wa : Wb;
    const int K = (part == 0) ? Ka : Kb;
    for (int k0 = 0; k0 < K; k0 += BK) {
      __syncthreads();
      // stage A tile (BM x BK): global row-major (stride K) -> As[k][m]
#pragma unroll
      for (int r = 0; r < 4; ++r) {
        int f = tid + 256 * r;          // [0,1024)
        int m = f >> 3, q = f & 7;
        int gm = mbase + m;
        float4 val = make_float4(0.f, 0.f, 0.f, 0.f);
        if (gm < M) val = *(const float4*)(Ap + (size_t)gm * K + k0 + q * 4);
        if (IN_RELU) {
          val.x = fmaxf(val.x, 0.f); val.y = fmaxf(val.y, 0.f);
          val.z = fmaxf(val.z, 0.f); val.w = fmaxf(val.w, 0.f);
        }
        As[q * 4 + 0][m] = val.x; As[q * 4 + 1][m] = val.y;
        As[q * 4 + 2][m] = val.z; As[q * 4 + 3][m] = val.w;
      }
      // stage W tile (BN x BK): W row-major (stride WS) -> Ws[k][c]
      for (int f = tid; f < BN * 8; f += 256) {
        int c = f >> 3, q = f & 7;
        float4 wv = make_float4(0.f, 0.f, 0.f, 0.f);
        if (c < NC) wv = *(const float4*)(Wp + (size_t)c * WS + k0 + q * 4);
        Ws[q * 4 + 0][c] = wv.x; Ws[q * 4 + 1][c] = wv.y;
        Ws[q * 4 + 2][c] = wv.z; Ws[q * 4 + 3][c] = wv.w;
      }
      __syncthreads();
#pragma unroll 4
      for (int k = 0; k < BK; ++k) {
        float4 a0 = *(const float4*)&As[k][ty * 8];
        float4 a1 = *(const float4*)&As[k][ty * 8 + 4];
        float a[8] = {a0.x, a0.y, a0.z, a0.w, a1.x, a1.y, a1.z, a1.w};
        float w[CPT];
#pragma unroll
        for (int j = 0; j < CPT; ++j) w[j] = Ws[k][tx + 16 * j];
#pragma unroll
        for (int i = 0; i < 8; ++i)
#pragma unroll
          for (int j = 0; j < CPT; ++j) acc[i][j] += a[i] * w[j];
      }
    }
  }
#pragma unroll
  for (int i = 0; i < 8; ++i) {
    int gm = mbase + ty * 8 + i;
    if (gm >= M) continue;
#pragma unroll
    for (int j = 0; j < CPT; ++j) {
      int c = tx + 16 * j;
      if (c < NC) C[(size_t)gm * NC + c] = acc[i][j] + bias[c];
    }
  }
}

// ---------------- BatchNorm (training-mode batch stats) ----------------

__global__ void colstats_kernel(const float* __restrict__ buf, float* __restrict__ stats, int n) {
  int c = threadIdx.x & 127;
  int half = threadIdx.x >> 7;  // 0/1
  float s = 0.f, q = 0.f;
  for (int r = blockIdx.x * 2 + half; r < n; r += gridDim.x * 2) {
    float x = buf[(size_t)r * HID + c];
    s += x; q += x * x;
  }
  atomicAdd(stats + c, s);
  atomicAdd(stats + HID + c, q);
}

__global__ void bn_kernel(float* buf, const float* __restrict__ stats,
                          const float* __restrict__ gamma, const float* __restrict__ beta,
                          int n, int act /*0=relu,1=sigmoid*/) {
  int i4 = blockIdx.x * blockDim.x + threadIdx.x;
  if (i4 >= n * (HID / 4)) return;
  int c0 = (i4 & 31) * 4;
  float4 x = ((float4*)buf)[i4];
  float inv_n = 1.0f / (float)n;
  float* xs = &x.x;
#pragma unroll
  for (int d = 0; d < 4; ++d) {
    int c = c0 + d;
    float mu = stats[c] * inv_n;
    float var = stats[HID + c] * inv_n - mu * mu;  // biased variance
    float y = (xs[d] - mu) * rsqrtf(var + 1e-5f) * gamma[c] + beta[c];
    xs[d] = (act == 0) ? fmaxf(y, 0.f) : 1.0f / (1.0f + expf(-y));
  }
  ((float4*)buf)[i4] = x;
}

// ---------------- log_softmax over 40 cols, wave per node ----------------

__global__ void logsoftmax_kernel(float* __restrict__ logits, int n) {
  int v = (blockIdx.x * blockDim.x + threadIdx.x) >> 6;
  int lane = threadIdx.x & 63;
  if (v >= n) return;
  float x = (lane < OUTC) ? logits[(size_t)v * OUTC + lane] : -3.4e38f;
  float m = x;
#pragma unroll
  for (int o = 32; o > 0; o >>= 1) m = fmaxf(m, __shfl_xor(m, o));
  float e = (lane < OUTC) ? expf(x - m) : 0.f;
  float s = e;
#pragma unroll
  for (int o = 32; o > 0; o >>= 1) s += __shfl_xor(s, o);
  if (lane < OUTC) logits[(size_t)v * OUTC + lane] = x - m - logf(s);
}

// ---------------- launch ----------------

extern "C" void kernel_launch(void* const* d_in, const int* in_sizes, int n_in,
                              void* d_out, int out_size, void* d_ws, size_t ws_size,
                              hipStream_t stream) {
  const float* x       = (const float*)d_in[0];
  const float* alpha   = (const float*)d_in[1];
  const int*   eidx    = (const int*)d_in[2];
  const float* sage_Wl = (const float*)d_in[3];
  const float* sage_bl = (const float*)d_in[4];
  const float* sage_Wr = (const float*)d_in[5];
  const float* sage_g  = (const float*)d_in[6];
  const float* sage_b  = (const float*)d_in[7];
  const float* W0 = (const float*)d_in[8];
  const float* b0 = (const float*)d_in[9];
  const float* W1 = (const float*)d_in[10];
  const float* b1 = (const float*)d_in[11];
  const float* W2 = (const float*)d_in[12];
  const float* b2 = (const float*)d_in[13];
  const float* mg = (const float*)d_in[14];
  const float* mb = (const float*)d_in[15];
  const float* Wc = (const float*)d_in[16];
  const float* bc = (const float*)d_in[17];
  const float* temp = (const float*)d_in[18];
  float* out = (float*)d_out;

  const int n = in_sizes[0] / HID;  // 100000
  const int e = in_sizes[2] / 2;    // 1600000
  const int* src = eidx;
  const int* tgt = eidx + e;

  // workspace layout
  float* ws = (float*)d_ws;
  float* bufA  = ws;                          // N*128
  float* bufB  = bufA + (size_t)n * HID;      // N*128
  float* sim   = bufB + (size_t)n * HID;      // N
  float* rn    = sim + n;                     // N
  float* stats = rn + n;                      // 1024 (4 BN passes x 256)
  int* cnt    = (int*)(stats + 1024);         // N
  int* rowptr = cnt + n;                      // N+1
  int* cursor = rowptr + n + 1;               // N
  int* csr    = cursor + n;                   // E
  int* blks   = csr + e;                      // 256

  const int T = 256;
  const int nb_scan = (n + SCAN_ELEMS - 1) / SCAN_ELEMS;  // 49

  // ---- graph prep + gate (independent of SAGE compute) ----
  init_kernel<<<(n + T - 1) / T, T, 0, stream>>>(cnt, sim, stats, n);
  rnorm_kernel<<<(int)(((size_t)n * 16 + T - 1) / T), T, 0, stream>>>(alpha, rn, n);
  count_kernel<<<(e + T - 1) / T, T, 0, stream>>>(tgt, cnt, e);
  scan1_kernel<<<nb_scan, SCAN_T, 0, stream>>>(cnt, rowptr, blks, n);
  scan2_kernel<<<1, SCAN_T, 0, stream>>>(blks, nb_scan);
  scan3_kernel<<<(n + 1 + T - 1) / T, T, 0, stream>>>(rowptr, cursor, blks, n, e);
  scatter_kernel<<<(e + T - 1) / T, T, 0, stream>>>(src, tgt, cursor, csr, e);
  gate_edge_kernel<<<(int)(((size_t)e * 16 + T - 1) / T), T, 0, stream>>>(alpha, src, tgt, rn, sim, e);
  gate_final_kernel<<<(n + T - 1) / T, T, 0, stream>>>(sim, cnt, temp, out + (size_t)n * OUTC, n);

  const int gLin = (n + 127) / 128;
  const int gAgg = (int)(((size_t)n * 32 + T - 1) / T);
  const int gBn  = (int)(((size_t)n * 32 + T - 1) / T);
  const int gCs  = 512;

  // ---- SAGE layer 0 (h=x) ----
  aggregate_kernel<<<gAgg, T, 0, stream>>>(x, rowptr, csr, bufB, n);
  lin_kernel<128, true, false><<<gLin, T, 0, stream>>>(
      bufB, HID, x, HID, sage_Wl, sage_Wr, HID, sage_bl, bufB, n, HID);
  colstats_kernel<<<gCs, T, 0, stream>>>(bufB, stats, n);
  bn_kernel<<<gBn, T, 0, stream>>>(bufB, stats, sage_g, sage_b, n, 0);
  // ---- SAGE layer 1 ----
  aggregate_kernel<<<gAgg, T, 0, stream>>>(bufB, rowptr, csr, bufA, n);
  lin_kernel<128, true, false><<<gLin, T, 0, stream>>>(
      bufA, HID, bufB, HID, sage_Wl + HID * HID, sage_Wr + HID * HID, HID,
      sage_bl + HID, bufA, n, HID);
  colstats_kernel<<<gCs, T, 0, stream>>>(bufA, stats + 256, n);
  bn_kernel<<<gBn, T, 0, stream>>>(bufA, stats + 256, sage_g + HID, sage_b + HID, n, 0);
  // ---- SAGE layer 2 (no BN/relu) -> H_gnn in bufB ----
  aggregate_kernel<<<gAgg, T, 0, stream>>>(bufA, rowptr, csr, bufB, n);
  lin_kernel<128, true, false><<<gLin, T, 0, stream>>>(
      bufB, HID, bufA, HID, sage_Wl + 2 * HID * HID, sage_Wr + 2 * HID * HID, HID,
      sage_bl + 2 * HID, bufB, n, HID);

  // ---- Proto MLP -> H_proto in bufA ----
  lin_kernel<128, false, false><<<gLin, T, 0, stream>>>(
      alpha, 64, nullptr, 0, W0, nullptr, 64, b0, bufA, n, HID);
  colstats_kernel<<<gCs, T, 0, stream>>>(bufA, stats + 512, n);
  bn_kernel<<<gBn, T, 0, stream>>>(bufA, stats + 512, mg, mb, n, 1);
  lin_kernel<128, false, false><<<gLin, T, 0, stream>>>(
      bufA, HID, nullptr, 0, W1, nullptr, HID, b1, bufA, n, HID);
  colstats_kernel<<<gCs, T, 0, stream>>>(bufA, stats + 768, n);
  bn_kernel<<<gBn, T, 0, stream>>>(bufA, stats + 768, mg + HID, mb + HID, n, 1);
  lin_kernel<128, false, false><<<gLin, T, 0, stream>>>(
      bufA, HID, nullptr, 0, W2, nullptr, HID, b2, bufA, n, HID);

  // ---- classifier: relu(concat) @ Wc^T + bc -> logits in d_out, then log_softmax ----
  lin_kernel<48, true, true><<<gLin, T, 0, stream>>>(
      bufB, HID, bufA, HID, Wc, Wc + HID, 2 * HID, bc, out, n, OUTC);
  logsoftmax_kernel<<<(int)(((size_t)n * 64 + T - 1) / T), T, 0, stream>>>(out, n);
}

// Round 3
// 1338.788 us; speedup vs baseline: 1.2920x; 1.2920x over previous
//
#include <hip/hip_runtime.h>
#include <cstdint>
#include <cstddef>

#define HID 128
#define OUTC 40
#define WTOT 139264  // Wl 49152 | Wr 49152 | W0 8192 | W1 16384 | W2 16384

typedef __attribute__((ext_vector_type(8))) short short8;
typedef __attribute__((ext_vector_type(4))) float floatx4;

__device__ __forceinline__ unsigned short f2b(float f) {
  unsigned int u = __float_as_uint(f);
  unsigned int r = u + 0x7FFFu + ((u >> 16) & 1u);
  return (unsigned short)(r >> 16);
}
__device__ __forceinline__ float blo(unsigned int u) { return __uint_as_float(u << 16); }
__device__ __forceinline__ float bhi(unsigned int u) { return __uint_as_float(u & 0xFFFF0000u); }
__device__ __forceinline__ unsigned int pack2(float a, float b) {
  return (unsigned int)f2b(a) | ((unsigned int)f2b(b) << 16);
}

__device__ __forceinline__ void async_cp16(const ushort* g, ushort* l) {
  __builtin_amdgcn_global_load_lds((const __attribute__((address_space(1))) void*)g,
                                   (__attribute__((address_space(3))) void*)l, 16, 0, 0);
}

// ---------------- small utility kernels ----------------

__global__ void init_kernel(int* __restrict__ cnt, float* __restrict__ sim,
                            float* __restrict__ stats, int n) {
  int idx = blockIdx.x * blockDim.x + threadIdx.x;
  if (idx < n) { cnt[idx] = 0; sim[idx] = 1.0f; }  // sim starts at self-loop dot = 1
  if (idx < 1024) stats[idx] = 0.0f;
}

__global__ void cvt_kernel(const float* __restrict__ in, ushort* __restrict__ out, int n4) {
  int i = blockIdx.x * blockDim.x + threadIdx.x;
  if (i >= n4) return;
  float4 v = ((const float4*)in)[i];
  ushort4 o;
  o.x = f2b(v.x); o.y = f2b(v.y); o.z = f2b(v.z); o.w = f2b(v.w);
  ((ushort4*)out)[i] = o;
}

// weights: [Wl 49152][Wr 49152][W0 8192][W1 16384][W2 16384] = 139264 elems
__global__ void cvtw_kernel(const float* __restrict__ Wl, const float* __restrict__ Wr,
                            const float* __restrict__ W0, const float* __restrict__ W1,
                            const float* __restrict__ W2, ushort* __restrict__ wb) {
  int e4 = (blockIdx.x * blockDim.x + threadIdx.x) * 4;
  if (e4 >= WTOT) return;
  const float* s; int off;
  if (e4 < 49152)       { s = Wl; off = 0; }
  else if (e4 < 98304)  { s = Wr; off = 49152; }
  else if (e4 < 106496) { s = W0; off = 98304; }
  else if (e4 < 122880) { s = W1; off = 106496; }
  else                  { s = W2; off = 122880; }
  float4 v = *(const float4*)(s + (e4 - off));
  ushort4 o;
  o.x = f2b(v.x); o.y = f2b(v.y); o.z = f2b(v.z); o.w = f2b(v.w);
  *(ushort4*)(wb + e4) = o;
}

__global__ void rnorm_kernel(const float* __restrict__ alpha, float* __restrict__ rn, int n) {
  int g = (blockIdx.x * blockDim.x + threadIdx.x) >> 4;
  int lane = threadIdx.x & 15;
  if (g >= n) return;
  const float4 a = *(const float4*)(alpha + (size_t)g * 64 + lane * 4);
  float d = a.x * a.x + a.y * a.y + a.z * a.z + a.w * a.w;
  d += __shfl_xor(d, 1); d += __shfl_xor(d, 2);
  d += __shfl_xor(d, 4); d += __shfl_xor(d, 8);
  if (lane == 0) rn[g] = 1.0f / fmaxf(sqrtf(d), 1e-12f);
}

__global__ void count_kernel(const int* __restrict__ tgt, int* __restrict__ cnt, int e) {
  int idx = blockIdx.x * blockDim.x + threadIdx.x;
  if (idx < e) atomicAdd(cnt + tgt[idx], 1);
}

// ---------------- exclusive scan (3-kernel) ----------------

#define SCAN_T 256
#define SCAN_VPT 8
#define SCAN_ELEMS 2048

__global__ void scan1_kernel(const int* __restrict__ cnt, int* __restrict__ rowptr,
                             int* __restrict__ blksum, int n) {
  __shared__ int sh[SCAN_T];
  int t = threadIdx.x;
  int base = blockIdx.x * SCAN_ELEMS + t * SCAN_VPT;
  int v[SCAN_VPT];
  int s = 0;
#pragma unroll
  for (int i = 0; i < SCAN_VPT; ++i) {
    int idx = base + i;
    v[i] = (idx < n) ? cnt[idx] : 0;
    s += v[i];
  }
  sh[t] = s;
  __syncthreads();
  for (int d = 1; d < SCAN_T; d <<= 1) {
    int add = (t >= d) ? sh[t - d] : 0;
    __syncthreads();
    sh[t] += add;
    __syncthreads();
  }
  int p = sh[t] - s;
#pragma unroll
  for (int i = 0; i < SCAN_VPT; ++i) {
    int idx = base + i;
    if (idx < n) rowptr[idx] = p;
    p += v[i];
  }
  if (t == SCAN_T - 1) blksum[blockIdx.x] = sh[t];
}

__global__ void scan2_kernel(int* __restrict__ blk, int nb) {
  __shared__ int sh[SCAN_T];
  int t = threadIdx.x;
  int s = (t < nb) ? blk[t] : 0;
  sh[t] = s;
  __syncthreads();
  for (int d = 1; d < SCAN_T; d <<= 1) {
    int add = (t >= d) ? sh[t - d] : 0;
    __syncthreads();
    sh[t] += add;
    __syncthreads();
  }
  if (t < nb) blk[t] = sh[t] - s;
}

__global__ void scan3_kernel(int* __restrict__ rowptr, int* __restrict__ cursor,
                             const int* __restrict__ blkoff, int n, int etot) {
  int idx = blockIdx.x * blockDim.x + threadIdx.x;
  if (idx < n) {
    int r = rowptr[idx] + blkoff[idx / SCAN_ELEMS];
    rowptr[idx] = r;
    cursor[idx] = r;
  } else if (idx == n) {
    rowptr[n] = etot;
  }
}

__global__ void scatter_kernel(const int* __restrict__ src, const int* __restrict__ tgt,
                               int* __restrict__ cursor, int* __restrict__ csr, int e) {
  int idx = blockIdx.x * blockDim.x + threadIdx.x;
  if (idx >= e) return;
  int v = tgt[idx];
  int pos = atomicAdd(cursor + v, 1);
  csr[pos] = src[idx];
}

// ---------------- gate (bf16 alpha) ----------------

__global__ void gate_edge_b(const ushort* __restrict__ ab, const int* __restrict__ src,
                            const int* __restrict__ tgt, const float* __restrict__ rn,
                            float* __restrict__ sim, int e) {
  int g = (blockIdx.x * blockDim.x + threadIdx.x) >> 3;  // 8 lanes / edge
  int lane = threadIdx.x & 7;
  if (g >= e) return;
  int u = src[g], v = tgt[g];
  uint4 a = *(const uint4*)(ab + (size_t)u * 64 + lane * 8);
  uint4 b = *(const uint4*)(ab + (size_t)v * 64 + lane * 8);
  float d = blo(a.x) * blo(b.x) + bhi(a.x) * bhi(b.x)
          + blo(a.y) * blo(b.y) + bhi(a.y) * bhi(b.y)
          + blo(a.z) * blo(b.z) + bhi(a.z) * bhi(b.z)
          + blo(a.w) * blo(b.w) + bhi(a.w) * bhi(b.w);
  d += __shfl_xor(d, 1); d += __shfl_xor(d, 2); d += __shfl_xor(d, 4);
  if (lane == 0) atomicAdd(sim + v, d * rn[u] * rn[v]);
}

__global__ void gate_final_kernel(const float* __restrict__ sim, const int* __restrict__ cnt,
                                  const float* __restrict__ temp, float* __restrict__ out, int n) {
  int v = blockIdx.x * blockDim.x + threadIdx.x;
  if (v >= n) return;
  float m = sim[v] / (float)(cnt[v] + 1);
  float t = temp[0];
  out[v] = 1.0f / (1.0f + expf(-t * m));
}

// ---------------- SAGE mean aggregation (bf16 in/out, f32 accumulate) ----------------

__global__ void agg_b_kernel(const ushort* __restrict__ h, const int* __restrict__ rowptr,
                             const int* __restrict__ csr, ushort* __restrict__ outb, int n) {
  int g = (blockIdx.x * blockDim.x + threadIdx.x) >> 4;  // 16 lanes / node
  int lane = threadIdx.x & 15;
  if (g >= n) return;
  int beg = rowptr[g], end = rowptr[g + 1];
  float a0=0,a1=0,a2=0,a3=0,a4=0,a5=0,a6=0,a7=0;
  int j = beg;
  for (; j + 1 < end; j += 2) {
    int u0 = csr[j], u1 = csr[j + 1];
    uint4 v0 = *(const uint4*)(h + (size_t)u0 * HID + lane * 8);
    uint4 v1 = *(const uint4*)(h + (size_t)u1 * HID + lane * 8);
    a0 += blo(v0.x) + blo(v1.x); a1 += bhi(v0.x) + bhi(v1.x);
    a2 += blo(v0.y) + blo(v1.y); a3 += bhi(v0.y) + bhi(v1.y);
    a4 += blo(v0.z) + blo(v1.z); a5 += bhi(v0.z) + bhi(v1.z);
    a6 += blo(v0.w) + blo(v1.w); a7 += bhi(v0.w) + bhi(v1.w);
  }
  if (j < end) {
    int u0 = csr[j];
    uint4 v0 = *(const uint4*)(h + (size_t)u0 * HID + lane * 8);
    a0 += blo(v0.x); a1 += bhi(v0.x); a2 += blo(v0.y); a3 += bhi(v0.y);
    a4 += blo(v0.z); a5 += bhi(v0.z); a6 += blo(v0.w); a7 += bhi(v0.w);
  }
  float r = (end > beg) ? 1.0f / (float)(end - beg) : 0.0f;
  uint4 o;
  o.x = pack2(a0 * r, a1 * r); o.y = pack2(a2 * r, a3 * r);
  o.z = pack2(a4 * r, a5 * r); o.w = pack2(a6 * r, a7 * r);
  *(uint4*)(outb + (size_t)g * HID + lane * 8) = o;
}

// ---------------- MFMA linear: C = A1@W1^T (+ A2@W2^T) + bias, bf16 in, bf16 out ----
// BM=128, NC=128 fixed, BK=32. 256 threads = 4 waves; wave w owns rows [w*32, w*32+32).
// LDS tiles staged via global_load_lds(16B) with XOR chunk swizzle (chunk q of row r
// stored at q ^ ((r>>1)&3)) -> conflict-free ds_read_b128 frag loads.
// Optional fused column stats (sum, sumsq) for BatchNorm.

template <int NPARTS, bool STATS>
__global__ __launch_bounds__(256) void mlin_kernel(
    const ushort* __restrict__ A1, const ushort* __restrict__ A2, int K,
    const ushort* __restrict__ W1, const ushort* __restrict__ W2,
    const float* __restrict__ bias, ushort* __restrict__ C,
    float* __restrict__ stats, int M) {
  __shared__ ushort As[128 * 32];
  __shared__ ushort Bs[128 * 32];
  const int tid = threadIdx.x;
  const int w = tid >> 6, l = tid & 63;
  const int mbase = blockIdx.x * 128;
  const int lm = l & 15, lq = l >> 4;
  floatx4 acc[2][8];
#pragma unroll
  for (int mt = 0; mt < 2; ++mt)
#pragma unroll
    for (int nt = 0; nt < 8; ++nt) {
      floatx4 z = {0.f, 0.f, 0.f, 0.f};
      acc[mt][nt] = z;
    }

  for (int part = 0; part < NPARTS; ++part) {
    const ushort* Ap = part ? A2 : A1;
    const ushort* Wp = part ? W2 : W1;
    for (int k0 = 0; k0 < K; k0 += 32) {
#pragma unroll
      for (int i = 0; i < 2; ++i) {
        int s = w * 2 + i;
        int rt = s * 16 + (l >> 2);
        int q = (l & 3) ^ ((rt >> 1) & 3);
        int grow = mbase + rt; grow = grow < M ? grow : M - 1;
        async_cp16(Ap + (size_t)grow * K + k0 + q * 8, &As[s * 512]);
        async_cp16(Wp + (size_t)rt * K + k0 + q * 8, &Bs[s * 512]);
      }
      __syncthreads();
      short8 b[8];
#pragma unroll
      for (int nt = 0; nt < 8; ++nt) {
        int row = nt * 16 + lm;
        int q = lq ^ ((row >> 1) & 3);
        b[nt] = *(const short8*)&Bs[row * 32 + q * 8];
      }
#pragma unroll
      for (int mt = 0; mt < 2; ++mt) {
        int row = (w * 2 + mt) * 16 + lm;
        int q = lq ^ ((row >> 1) & 3);
        short8 a = *(const short8*)&As[row * 32 + q * 8];
#pragma unroll
        for (int nt = 0; nt < 8; ++nt)
          acc[mt][nt] = __builtin_amdgcn_mfma_f32_16x16x32_bf16(a, b[nt], acc[mt][nt], 0, 0, 0);
      }
      __syncthreads();
    }
  }

  // epilogue: C/D layout col = lane&15, row = (lane>>4)*4 + reg
  float ss[8], qq[8];
#pragma unroll
  for (int nt = 0; nt < 8; ++nt) { ss[nt] = 0.f; qq[nt] = 0.f; }
#pragma unroll
  for (int nt = 0; nt < 8; ++nt) {
    int col = nt * 16 + lm;
    float bv = bias[col];
#pragma unroll
    for (int mt = 0; mt < 2; ++mt) {
      int rbase = mbase + (w * 2 + mt) * 16 + lq * 4;
#pragma unroll
      for (int r = 0; r < 4; ++r) {
        int grow = rbase + r;
        if (grow < M) {
          float val = acc[mt][nt][r] + bv;
          C[(size_t)grow * 128 + col] = f2b(val);
          if (STATS) { ss[nt] += val; qq[nt] += val * val; }
        }
      }
    }
  }
  if (STATS) {
    float* sred = (float*)As;  // safe: past last barrier, no more tile reads
    if (tid < 256) sred[tid] = 0.f;
    __syncthreads();
#pragma unroll
    for (int nt = 0; nt < 8; ++nt) {
      ss[nt] += __shfl_xor(ss[nt], 16); ss[nt] += __shfl_xor(ss[nt], 32);
      qq[nt] += __shfl_xor(qq[nt], 16); qq[nt] += __shfl_xor(qq[nt], 32);
    }
    if (lq == 0) {
#pragma unroll
      for (int nt = 0; nt < 8; ++nt) {
        int col = nt * 16 + lm;
        atomicAdd(&sred[col], ss[nt]);
        atomicAdd(&sred[128 + col], qq[nt]);
      }
    }
    __syncthreads();
    if (tid < 256) atomicAdd(&stats[tid], sred[tid]);
  }
}

// ---------------- BatchNorm apply (bf16 in-place) ----------------

__global__ void bnb_kernel(ushort* __restrict__ buf, const float* __restrict__ stats,
                           const float* __restrict__ gamma, const float* __restrict__ beta,
                           int n, int act /*0=relu,1=sigmoid*/) {
  int i8 = blockIdx.x * blockDim.x + threadIdx.x;
  if (i8 >= n * 16) return;
  int c0 = (i8 & 15) * 8;
  uint4 v = ((const uint4*)buf)[i8];
  float x[8] = {blo(v.x), bhi(v.x), blo(v.y), bhi(v.y),
                blo(v.z), bhi(v.z), blo(v.w), bhi(v.w)};
  float inv_n = 1.0f / (float)n;
#pragma unroll
  for (int d = 0; d < 8; ++d) {
    int c = c0 + d;
    float mu = stats[c] * inv_n;
    float var = stats[128 + c] * inv_n - mu * mu;
    float y = (x[d] - mu) * rsqrtf(var + 1e-5f) * gamma[c] + beta[c];
    x[d] = (act == 0) ? fmaxf(y, 0.f) : 1.0f / (1.0f + expf(-y));
  }
  uint4 o;
  o.x = pack2(x[0], x[1]); o.y = pack2(x[2], x[3]);
  o.z = pack2(x[4], x[5]); o.w = pack2(x[6], x[7]);
  ((uint4*)buf)[i8] = o;
}

// ---------------- classifier: relu([Hg|Hp]) @ Wc^T + bc (bf16 acts, f32 weights) ----

__global__ __launch_bounds__(256) void cls_kernel(
    const ushort* __restrict__ A, const ushort* __restrict__ B,
    const float* __restrict__ Wc, const float* __restrict__ bias,
    float* __restrict__ C, int M) {
  constexpr int BK = 32, BN = 48, CPT = 3;
  const int K = 128, WS = 256, NC = OUTC;
  __shared__ float As[BK][128 + 4];
  __shared__ float Ws[BK][BN + 1];
  const int tid = threadIdx.x;
  const int tx = tid & 15, ty = tid >> 4;
  const int mbase = blockIdx.x * 128;
  float acc[8][CPT];
#pragma unroll
  for (int i = 0; i < 8; ++i)
#pragma unroll
    for (int j = 0; j < CPT; ++j) acc[i][j] = 0.0f;

  for (int part = 0; part < 2; ++part) {
    const ushort* Ap = (part == 0) ? A : B;
    for (int k0 = 0; k0 < K; k0 += BK) {
      __syncthreads();
#pragma unroll
      for (int r = 0; r < 4; ++r) {
        int f = tid + 256 * r;
        int m = f >> 3, q = f & 7;
        int gm = mbase + m;
        float4 val = make_float4(0.f, 0.f, 0.f, 0.f);
        if (gm < M) {
          ushort4 t = *(const ushort4*)(Ap + (size_t)gm * K + k0 + q * 4);
          val.x = fmaxf(blo(t.x), 0.f); val.y = fmaxf(blo(t.y), 0.f);
          val.z = fmaxf(blo(t.z), 0.f); val.w = fmaxf(blo(t.w), 0.f);
        }
        As[q * 4 + 0][m] = val.x; As[q * 4 + 1][m] = val.y;
        As[q * 4 + 2][m] = val.z; As[q * 4 + 3][m] = val.w;
      }
      for (int f = tid; f < BN * 8; f += 256) {
        int c = f >> 3, q = f & 7;
        float4 wv = make_float4(0.f, 0.f, 0.f, 0.f);
        if (c < NC) wv = *(const float4*)(Wc + (size_t)c * WS + part * 128 + k0 + q * 4);
        Ws[q * 4 + 0][c] = wv.x; Ws[q * 4 + 1][c] = wv.y;
        Ws[q * 4 + 2][c] = wv.z; Ws[q * 4 + 3][c] = wv.w;
      }
      __syncthreads();
#pragma unroll 4
      for (int k = 0; k < BK; ++k) {
        float4 a0 = *(const float4*)&As[k][ty * 8];
        float4 a1 = *(const float4*)&As[k][ty * 8 + 4];
        float a[8] = {a0.x, a0.y, a0.z, a0.w, a1.x, a1.y, a1.z, a1.w};
        float wv[CPT];
#pragma unroll
        for (int j = 0; j < CPT; ++j) wv[j] = Ws[k][tx + 16 * j];
#pragma unroll
        for (int i = 0; i < 8; ++i)
#pragma unroll
          for (int j = 0; j < CPT; ++j) acc[i][j] += a[i] * wv[j];
      }
    }
  }
#pragma unroll
  for (int i = 0; i < 8; ++i) {
    int gm = mbase + ty * 8 + i;
    if (gm >= M) continue;
#pragma unroll
    for (int j = 0; j < CPT; ++j) {
      int c = tx + 16 * j;
      if (c < NC) C[(size_t)gm * NC + c] = acc[i][j] + bias[c];
    }
  }
}

// ---------------- log_softmax over 40 cols, wave per node ----------------

__global__ void logsoftmax_kernel(float* __restrict__ logits, int n) {
  int v = (blockIdx.x * blockDim.x + threadIdx.x) >> 6;
  int lane = threadIdx.x & 63;
  if (v >= n) return;
  float x = (lane < OUTC) ? logits[(size_t)v * OUTC + lane] : -3.4e38f;
  float m = x;
#pragma unroll
  for (int o = 32; o > 0; o >>= 1) m = fmaxf(m, __shfl_xor(m, o));
  float e = (lane < OUTC) ? expf(x - m) : 0.f;
  float s = e;
#pragma unroll
  for (int o = 32; o > 0; o >>= 1) s += __shfl_xor(s, o);
  if (lane < OUTC) logits[(size_t)v * OUTC + lane] = x - m - logf(s);
}

// ---------------- launch ----------------

extern "C" void kernel_launch(void* const* d_in, const int* in_sizes, int n_in,
                              void* d_out, int out_size, void* d_ws, size_t ws_size,
                              hipStream_t stream) {
  const float* x       = (const float*)d_in[0];
  const float* alpha   = (const float*)d_in[1];
  const int*   eidx    = (const int*)d_in[2];
  const float* sage_Wl = (const float*)d_in[3];
  const float* sage_bl = (const float*)d_in[4];
  const float* sage_Wr = (const float*)d_in[5];
  const float* sage_g  = (const float*)d_in[6];
  const float* sage_b  = (const float*)d_in[7];
  const float* W0 = (const float*)d_in[8];
  const float* b0 = (const float*)d_in[9];
  const float* W1 = (const float*)d_in[10];
  const float* b1 = (const float*)d_in[11];
  const float* W2 = (const float*)d_in[12];
  const float* b2 = (const float*)d_in[13];
  const float* mg = (const float*)d_in[14];
  const float* mb = (const float*)d_in[15];
  const float* Wc = (const float*)d_in[16];
  const float* bc = (const float*)d_in[17];
  const float* temp = (const float*)d_in[18];
  float* out = (float*)d_out;

  const int n = in_sizes[0] / HID;  // 100000
  const int e = in_sizes[2] / 2;    // 1600000
  const int* src = eidx;
  const int* tgt = eidx + e;

  // workspace layout (bf16 buffers first: 16B aligned)
  char* p = (char*)d_ws;
  ushort* xb     = (ushort*)p; p += (size_t)n * HID * 2;   // also hgnn (aliased, xb dead by then)
  ushort* hb     = (ushort*)p; p += (size_t)n * HID * 2;
  ushort* aggb   = (ushort*)p; p += (size_t)n * HID * 2;   // also ab (alpha bf16, N*64)
  ushort* hproto = (ushort*)p; p += (size_t)n * HID * 2;
  ushort* wb     = (ushort*)p; p += (size_t)WTOT * 2;
  float* sim   = (float*)p; p += (size_t)n * 4;
  float* rn    = (float*)p; p += (size_t)n * 4;
  float* stats = (float*)p; p += 1024 * 4;
  int* cnt    = (int*)p; p += (size_t)n * 4;
  int* rowptr = (int*)p; p += ((size_t)n + 1) * 4;
  int* cursor = (int*)p; p += (size_t)n * 4;
  int* csr    = (int*)p; p += (size_t)e * 4;
  int* blks   = (int*)p;
  ushort* ab   = aggb;
  ushort* hgnn = xb;
  ushort* Wlb = wb, *Wrb = wb + 49152, *W0b = wb + 98304, *W1b = wb + 106496, *W2b = wb + 122880;

  const int T = 256;
  const int nb_scan = (n + SCAN_ELEMS - 1) / SCAN_ELEMS;

  // ---- init + converts + graph prep + gate ----
  init_kernel<<<(n + T - 1) / T, T, 0, stream>>>(cnt, sim, stats, n);
  cvt_kernel<<<(n * (HID / 4) + T - 1) / T, T, 0, stream>>>(x, xb, n * (HID / 4));
  cvt_kernel<<<(n * 16 + T - 1) / T, T, 0, stream>>>(alpha, ab, n * 16);
  cvtw_kernel<<<(WTOT / 4 + T - 1) / T, T, 0, stream>>>(sage_Wl, sage_Wr, W0, W1, W2, wb);
  rnorm_kernel<<<(int)(((size_t)n * 16 + T - 1) / T), T, 0, stream>>>(alpha, rn, n);
  count_kernel<<<(e + T - 1) / T, T, 0, stream>>>(tgt, cnt, e);
  scan1_kernel<<<nb_scan, SCAN_T, 0, stream>>>(cnt, rowptr, blks, n);
  scan2_kernel<<<1, SCAN_T, 0, stream>>>(blks, nb_scan);
  scan3_kernel<<<(n + 1 + T - 1) / T, T, 0, stream>>>(rowptr, cursor, blks, n, e);
  scatter_kernel<<<(e + T - 1) / T, T, 0, stream>>>(src, tgt, cursor, csr, e);
  gate_edge_b<<<(int)(((size_t)e * 8 + T - 1) / T), T, 0, stream>>>(ab, src, tgt, rn, sim, e);
  gate_final_kernel<<<(n + T - 1) / T, T, 0, stream>>>(sim, cnt, temp, out + (size_t)n * OUTC, n);

  const int gLin = (n + 127) / 128;
  const int gElem = (n * 16 + T - 1) / T;

  // ---- Proto MLP first (ab aliases aggb; must finish before SAGE aggregates) ----
  mlin_kernel<1, true><<<gLin, T, 0, stream>>>(ab, nullptr, 64, W0b, nullptr, b0, hb, stats + 512, n);
  bnb_kernel<<<gElem, T, 0, stream>>>(hb, stats + 512, mg, mb, n, 1);
  mlin_kernel<1, true><<<gLin, T, 0, stream>>>(hb, nullptr, 128, W1b, nullptr, b1, hb, stats + 768, n);
  bnb_kernel<<<gElem, T, 0, stream>>>(hb, stats + 768, mg + HID, mb + HID, n, 1);
  mlin_kernel<1, false><<<gLin, T, 0, stream>>>(hb, nullptr, 128, W2b, nullptr, b2, hproto, nullptr, n);

  // ---- SAGE ----
  agg_b_kernel<<<gElem, T, 0, stream>>>(xb, rowptr, csr, aggb, n);
  mlin_kernel<2, true><<<gLin, T, 0, stream>>>(aggb, xb, 128, Wlb, Wrb, sage_bl, hb, stats + 0, n);
  bnb_kernel<<<gElem, T, 0, stream>>>(hb, stats + 0, sage_g, sage_b, n, 0);
  agg_b_kernel<<<gElem, T, 0, stream>>>(hb, rowptr, csr, aggb, n);
  mlin_kernel<2, true><<<gLin, T, 0, stream>>>(aggb, hb, 128, Wlb + 16384, Wrb + 16384,
                                               sage_bl + HID, hb, stats + 256, n);
  bnb_kernel<<<gElem, T, 0, stream>>>(hb, stats + 256, sage_g + HID, sage_b + HID, n, 0);
  agg_b_kernel<<<gElem, T, 0, stream>>>(hb, rowptr, csr, aggb, n);
  mlin_kernel<2, false><<<gLin, T, 0, stream>>>(aggb, hb, 128, Wlb + 32768, Wrb + 32768,
                                                sage_bl + 2 * HID, hgnn, nullptr, n);

  // ---- classifier + log_softmax ----
  cls_kernel<<<gLin, T, 0, stream>>>(hgnn, hproto, Wc, bc, out, n);
  logsoftmax_kernel<<<(int)(((size_t)n * 64 + T - 1) / T), T, 0, stream>>>(out, n);
}

// Round 4
// 1145.008 us; speedup vs baseline: 1.5106x; 1.1692x over previous
//
#include <hip/hip_runtime.h>
#include <cstdint>
#include <cstddef>

#define HID 128
#define OUTC 40
#define WTOT 139264  // Wl 49152 | Wr 49152 | W0 8192 | W1 16384 | W2 16384
#define PB 200       // blocks for edge-binning passes
#define NBK_MAX 256  // max buckets (512 nodes each)

typedef __attribute__((ext_vector_type(8))) short short8;
typedef __attribute__((ext_vector_type(4))) float floatx4;

__device__ __forceinline__ unsigned short f2b(float f) {
  unsigned int u = __float_as_uint(f);
  unsigned int r = u + 0x7FFFu + ((u >> 16) & 1u);
  return (unsigned short)(r >> 16);
}
__device__ __forceinline__ float blo(unsigned int u) { return __uint_as_float(u << 16); }
__device__ __forceinline__ float bhi(unsigned int u) { return __uint_as_float(u & 0xFFFF0000u); }
__device__ __forceinline__ unsigned int pack2(float a, float b) {
  return (unsigned int)f2b(a) | ((unsigned int)f2b(b) << 16);
}

__device__ __forceinline__ void async_cp16(const ushort* g, ushort* l) {
  __builtin_amdgcn_global_load_lds((const __attribute__((address_space(1))) void*)g,
                                   (__attribute__((address_space(3))) void*)l, 16, 0, 0);
}

// ---------------- small utility kernels ----------------

__global__ void init_kernel(float* __restrict__ stats) {
  int idx = blockIdx.x * blockDim.x + threadIdx.x;
  if (idx < 1024) stats[idx] = 0.0f;
}

__global__ void cvt_kernel(const float* __restrict__ in, ushort* __restrict__ out, int n4) {
  int i = blockIdx.x * blockDim.x + threadIdx.x;
  if (i >= n4) return;
  float4 v = ((const float4*)in)[i];
  ushort4 o;
  o.x = f2b(v.x); o.y = f2b(v.y); o.z = f2b(v.z); o.w = f2b(v.w);
  ((ushort4*)out)[i] = o;
}

// weights: [Wl 49152][Wr 49152][W0 8192][W1 16384][W2 16384] = 139264 elems
__global__ void cvtw_kernel(const float* __restrict__ Wl, const float* __restrict__ Wr,
                            const float* __restrict__ W0, const float* __restrict__ W1,
                            const float* __restrict__ W2, ushort* __restrict__ wb) {
  int e4 = (blockIdx.x * blockDim.x + threadIdx.x) * 4;
  if (e4 >= WTOT) return;
  const float* s; int off;
  if (e4 < 49152)       { s = Wl; off = 0; }
  else if (e4 < 98304)  { s = Wr; off = 49152; }
  else if (e4 < 106496) { s = W0; off = 98304; }
  else if (e4 < 122880) { s = W1; off = 106496; }
  else                  { s = W2; off = 122880; }
  float4 v = *(const float4*)(s + (e4 - off));
  ushort4 o;
  o.x = f2b(v.x); o.y = f2b(v.y); o.z = f2b(v.z); o.w = f2b(v.w);
  *(ushort4*)(wb + e4) = o;
}

// normalized alpha -> bf16 (an = alpha / max(||alpha||, 1e-12))
__global__ void anorm_kernel(const float* __restrict__ alpha, ushort* __restrict__ anb, int n) {
  int g = (blockIdx.x * blockDim.x + threadIdx.x) >> 4;  // 16 lanes/node
  int lane = threadIdx.x & 15;
  if (g >= n) return;
  const float4 a = *(const float4*)(alpha + (size_t)g * 64 + lane * 4);
  float d = a.x * a.x + a.y * a.y + a.z * a.z + a.w * a.w;
  d += __shfl_xor(d, 1); d += __shfl_xor(d, 2);
  d += __shfl_xor(d, 4); d += __shfl_xor(d, 8);
  float r = 1.0f / fmaxf(sqrtf(d), 1e-12f);
  ushort4 o;
  o.x = f2b(a.x * r); o.y = f2b(a.y * r); o.z = f2b(a.z * r); o.w = f2b(a.w * r);
  *(ushort4*)(anb + (size_t)g * 64 + lane * 4) = o;
}

// ---------------- exclusive scan (generic, for the bucket table) ----------------

#define SCAN_T 256
#define SCAN_VPT 8
#define SCAN_ELEMS 2048

__global__ void scan1_kernel(const int* __restrict__ cnt, int* __restrict__ outp,
                             int* __restrict__ blksum, int n) {
  __shared__ int sh[SCAN_T];
  int t = threadIdx.x;
  int base = blockIdx.x * SCAN_ELEMS + t * SCAN_VPT;
  int v[SCAN_VPT];
  int s = 0;
#pragma unroll
  for (int i = 0; i < SCAN_VPT; ++i) {
    int idx = base + i;
    v[i] = (idx < n) ? cnt[idx] : 0;
    s += v[i];
  }
  sh[t] = s;
  __syncthreads();
  for (int d = 1; d < SCAN_T; d <<= 1) {
    int add = (t >= d) ? sh[t - d] : 0;
    __syncthreads();
    sh[t] += add;
    __syncthreads();
  }
  int p = sh[t] - s;
#pragma unroll
  for (int i = 0; i < SCAN_VPT; ++i) {
    int idx = base + i;
    if (idx < n) outp[idx] = p;
    p += v[i];
  }
  if (t == SCAN_T - 1) blksum[blockIdx.x] = sh[t];
}

__global__ void scan2_kernel(int* __restrict__ blk, int nb) {
  __shared__ int sh[SCAN_T];
  int t = threadIdx.x;
  int s = (t < nb) ? blk[t] : 0;
  sh[t] = s;
  __syncthreads();
  for (int d = 1; d < SCAN_T; d <<= 1) {
    int add = (t >= d) ? sh[t - d] : 0;
    __syncthreads();
    sh[t] += add;
    __syncthreads();
  }
  if (t < nb) blk[t] = sh[t] - s;
}

__global__ void scan3g_kernel(int* __restrict__ outp, const int* __restrict__ blkoff, int n) {
  int idx = blockIdx.x * blockDim.x + threadIdx.x;
  if (idx < n) outp[idx] += blkoff[idx / SCAN_ELEMS];
}

// ---------------- bucketed CSR build (no global atomics, coalesced-ish writes) ----

// Pass A: per-block histogram over buckets (tgt>>9) -> G[b*PB + blk]
__global__ void binA_kernel(const int* __restrict__ tgt, int* __restrict__ G,
                            int e, int chunk, int nbk) {
  __shared__ int hist[NBK_MAX];
  int tid = threadIdx.x;
  for (int b = tid; b < nbk; b += 256) hist[b] = 0;
  __syncthreads();
  int i0 = blockIdx.x * chunk;
  int i1 = min(e, i0 + chunk);
  for (int j = i0 + tid; j < i1; j += 256) atomicAdd(&hist[tgt[j] >> 9], 1);
  __syncthreads();
  for (int b = tid; b < nbk; b += 256) G[b * PB + blockIdx.x] = hist[b];
}

// Pass B: bin edges into per-(bucket,block) segments; value packs (tgt&511)<<17 | src
__global__ void binB_kernel(const int* __restrict__ src, const int* __restrict__ tgt,
                            const int* __restrict__ Gs, int* __restrict__ ebuf,
                            int e, int chunk, int nbk) {
  __shared__ int cur[NBK_MAX];
  int tid = threadIdx.x;
  for (int b = tid; b < nbk; b += 256) cur[b] = Gs[b * PB + blockIdx.x];
  __syncthreads();
  int i0 = blockIdx.x * chunk;
  int i1 = min(e, i0 + chunk);
  for (int j = i0 + tid; j < i1; j += 256) {
    int t = tgt[j];
    int pos = atomicAdd(&cur[t >> 9], 1);
    ebuf[pos] = ((t & 511) << 17) | src[j];
  }
}

// Pass C: one block per bucket -> exact CSR (csr, rowptr), all within bucket segment
__global__ void binC_kernel(const int* __restrict__ ebuf, const int* __restrict__ Gs,
                            int* __restrict__ rowptr, int* __restrict__ csr,
                            int n, int e, int nbk) {
  __shared__ int hist[512];
  __shared__ int scanbuf[256];
  int b = blockIdx.x, tid = threadIdx.x;
  int seg0 = Gs[b * PB];
  int seg1 = (b + 1 < nbk) ? Gs[(b + 1) * PB] : e;
  hist[tid] = 0; hist[tid + 256] = 0;
  __syncthreads();
  for (int j = seg0 + tid; j < seg1; j += 256)
    atomicAdd(&hist[ebuf[j] >> 17], 1);
  __syncthreads();
  int a0 = hist[2 * tid], a1 = hist[2 * tid + 1];
  int s = a0 + a1;
  scanbuf[tid] = s;
  __syncthreads();
  for (int d = 1; d < 256; d <<= 1) {
    int add = (tid >= d) ? scanbuf[tid - d] : 0;
    __syncthreads();
    scanbuf[tid] += add;
    __syncthreads();
  }
  int ex = scanbuf[tid] - s;  // exclusive over node pairs
  hist[2 * tid] = ex;
  hist[2 * tid + 1] = ex + a0;
  int node0 = b * 512 + 2 * tid;
  if (node0 < n) rowptr[node0] = seg0 + ex;
  if (node0 + 1 < n) rowptr[node0 + 1] = seg0 + ex + a0;
  __syncthreads();
  for (int j = seg0 + tid; j < seg1; j += 256) {
    int val = ebuf[j];
    int pos = atomicAdd(&hist[val >> 17], 1);
    csr[seg0 + pos] = val & 0x1FFFF;
  }
  if (b == nbk - 1 && tid == 0) rowptr[n] = e;
}

// ---------------- gate: pull-based, fused sigmoid (no atomics) ----------------

__global__ void gate_pull_kernel(const ushort* __restrict__ anb, const int* __restrict__ rowptr,
                                 const int* __restrict__ csr, const float* __restrict__ temp,
                                 float* __restrict__ out, int n) {
  int g = (blockIdx.x * blockDim.x + threadIdx.x) >> 3;  // 8 lanes/node
  int lane = threadIdx.x & 7;
  if (g >= n) return;
  uint4 av = *(const uint4*)(anb + (size_t)g * 64 + lane * 8);
  int beg = rowptr[g], end = rowptr[g + 1];
  float acc = 0.f;
  int j = beg;
  for (; j + 1 < end; j += 2) {
    int u0 = csr[j], u1 = csr[j + 1];
    uint4 b0 = *(const uint4*)(anb + (size_t)u0 * 64 + lane * 8);
    uint4 b1 = *(const uint4*)(anb + (size_t)u1 * 64 + lane * 8);
    acc += blo(av.x) * (blo(b0.x) + blo(b1.x)) + bhi(av.x) * (bhi(b0.x) + bhi(b1.x))
         + blo(av.y) * (blo(b0.y) + blo(b1.y)) + bhi(av.y) * (bhi(b0.y) + bhi(b1.y))
         + blo(av.z) * (blo(b0.z) + blo(b1.z)) + bhi(av.z) * (bhi(b0.z) + bhi(b1.z))
         + blo(av.w) * (blo(b0.w) + blo(b1.w)) + bhi(av.w) * (bhi(b0.w) + bhi(b1.w));
  }
  if (j < end) {
    int u0 = csr[j];
    uint4 b0 = *(const uint4*)(anb + (size_t)u0 * 64 + lane * 8);
    acc += blo(av.x) * blo(b0.x) + bhi(av.x) * bhi(b0.x)
         + blo(av.y) * blo(b0.y) + bhi(av.y) * bhi(b0.y)
         + blo(av.z) * blo(b0.z) + bhi(av.z) * bhi(b0.z)
         + blo(av.w) * blo(b0.w) + bhi(av.w) * bhi(b0.w);
  }
  acc += __shfl_xor(acc, 1); acc += __shfl_xor(acc, 2); acc += __shfl_xor(acc, 4);
  if (lane == 0) {
    float m = (1.0f + acc) / (float)(end - beg + 1);  // self-loop dot = 1
    out[g] = 1.0f / (1.0f + expf(-temp[0] * m));
  }
}

// ---------------- SAGE mean aggregation (bf16 in/out, f32 accumulate) ----------------

__global__ void agg_b_kernel(const ushort* __restrict__ h, const int* __restrict__ rowptr,
                             const int* __restrict__ csr, ushort* __restrict__ outb, int n) {
  int g = (blockIdx.x * blockDim.x + threadIdx.x) >> 4;  // 16 lanes / node
  int lane = threadIdx.x & 15;
  if (g >= n) return;
  int beg = rowptr[g], end = rowptr[g + 1];
  float a0=0,a1=0,a2=0,a3=0,a4=0,a5=0,a6=0,a7=0;
  int j = beg;
  for (; j + 3 < end; j += 4) {
    int u0 = csr[j], u1 = csr[j + 1], u2 = csr[j + 2], u3 = csr[j + 3];
    uint4 v0 = *(const uint4*)(h + (size_t)u0 * HID + lane * 8);
    uint4 v1 = *(const uint4*)(h + (size_t)u1 * HID + lane * 8);
    uint4 v2 = *(const uint4*)(h + (size_t)u2 * HID + lane * 8);
    uint4 v3 = *(const uint4*)(h + (size_t)u3 * HID + lane * 8);
    a0 += (blo(v0.x) + blo(v1.x)) + (blo(v2.x) + blo(v3.x));
    a1 += (bhi(v0.x) + bhi(v1.x)) + (bhi(v2.x) + bhi(v3.x));
    a2 += (blo(v0.y) + blo(v1.y)) + (blo(v2.y) + blo(v3.y));
    a3 += (bhi(v0.y) + bhi(v1.y)) + (bhi(v2.y) + bhi(v3.y));
    a4 += (blo(v0.z) + blo(v1.z)) + (blo(v2.z) + blo(v3.z));
    a5 += (bhi(v0.z) + bhi(v1.z)) + (bhi(v2.z) + bhi(v3.z));
    a6 += (blo(v0.w) + blo(v1.w)) + (blo(v2.w) + blo(v3.w));
    a7 += (bhi(v0.w) + bhi(v1.w)) + (bhi(v2.w) + bhi(v3.w));
  }
  for (; j < end; ++j) {
    int u0 = csr[j];
    uint4 v0 = *(const uint4*)(h + (size_t)u0 * HID + lane * 8);
    a0 += blo(v0.x); a1 += bhi(v0.x); a2 += blo(v0.y); a3 += bhi(v0.y);
    a4 += blo(v0.z); a5 += bhi(v0.z); a6 += blo(v0.w); a7 += bhi(v0.w);
  }
  float r = (end > beg) ? 1.0f / (float)(end - beg) : 0.0f;
  uint4 o;
  o.x = pack2(a0 * r, a1 * r); o.y = pack2(a2 * r, a3 * r);
  o.z = pack2(a4 * r, a5 * r); o.w = pack2(a6 * r, a7 * r);
  *(uint4*)(outb + (size_t)g * HID + lane * 8) = o;
}

// ---------------- MFMA linear: C = A1@W1^T (+ A2@W2^T) + bias, bf16 in, bf16 out ----

template <int NPARTS, bool STATS>
__global__ __launch_bounds__(256) void mlin_kernel(
    const ushort* __restrict__ A1, const ushort* __restrict__ A2, int K,
    const ushort* __restrict__ W1, const ushort* __restrict__ W2,
    const float* __restrict__ bias, ushort* __restrict__ C,
    float* __restrict__ stats, int M) {
  __shared__ ushort As[128 * 32];
  __shared__ ushort Bs[128 * 32];
  const int tid = threadIdx.x;
  const int w = tid >> 6, l = tid & 63;
  const int mbase = blockIdx.x * 128;
  const int lm = l & 15, lq = l >> 4;
  floatx4 acc[2][8];
#pragma unroll
  for (int mt = 0; mt < 2; ++mt)
#pragma unroll
    for (int nt = 0; nt < 8; ++nt) {
      floatx4 z = {0.f, 0.f, 0.f, 0.f};
      acc[mt][nt] = z;
    }

  for (int part = 0; part < NPARTS; ++part) {
    const ushort* Ap = part ? A2 : A1;
    const ushort* Wp = part ? W2 : W1;
    for (int k0 = 0; k0 < K; k0 += 32) {
#pragma unroll
      for (int i = 0; i < 2; ++i) {
        int s = w * 2 + i;
        int rt = s * 16 + (l >> 2);
        int q = (l & 3) ^ ((rt >> 1) & 3);
        int grow = mbase + rt; grow = grow < M ? grow : M - 1;
        async_cp16(Ap + (size_t)grow * K + k0 + q * 8, &As[s * 512]);
        async_cp16(Wp + (size_t)rt * K + k0 + q * 8, &Bs[s * 512]);
      }
      __syncthreads();
      short8 b[8];
#pragma unroll
      for (int nt = 0; nt < 8; ++nt) {
        int row = nt * 16 + lm;
        int q = lq ^ ((row >> 1) & 3);
        b[nt] = *(const short8*)&Bs[row * 32 + q * 8];
      }
#pragma unroll
      for (int mt = 0; mt < 2; ++mt) {
        int row = (w * 2 + mt) * 16 + lm;
        int q = lq ^ ((row >> 1) & 3);
        short8 a = *(const short8*)&As[row * 32 + q * 8];
#pragma unroll
        for (int nt = 0; nt < 8; ++nt)
          acc[mt][nt] = __builtin_amdgcn_mfma_f32_16x16x32_bf16(a, b[nt], acc[mt][nt], 0, 0, 0);
      }
      __syncthreads();
    }
  }

  // epilogue: C/D layout col = lane&15, row = (lane>>4)*4 + reg
  float ss[8], qq[8];
#pragma unroll
  for (int nt = 0; nt < 8; ++nt) { ss[nt] = 0.f; qq[nt] = 0.f; }
#pragma unroll
  for (int nt = 0; nt < 8; ++nt) {
    int col = nt * 16 + lm;
    float bv = bias[col];
#pragma unroll
    for (int mt = 0; mt < 2; ++mt) {
      int rbase = mbase + (w * 2 + mt) * 16 + lq * 4;
#pragma unroll
      for (int r = 0; r < 4; ++r) {
        int grow = rbase + r;
        if (grow < M) {
          float val = acc[mt][nt][r] + bv;
          C[(size_t)grow * 128 + col] = f2b(val);
          if (STATS) { ss[nt] += val; qq[nt] += val * val; }
        }
      }
    }
  }
  if (STATS) {
    float* sred = (float*)As;  // safe: past last barrier, no more tile reads
    if (tid < 256) sred[tid] = 0.f;
    __syncthreads();
#pragma unroll
    for (int nt = 0; nt < 8; ++nt) {
      ss[nt] += __shfl_xor(ss[nt], 16); ss[nt] += __shfl_xor(ss[nt], 32);
      qq[nt] += __shfl_xor(qq[nt], 16); qq[nt] += __shfl_xor(qq[nt], 32);
    }
    if (lq == 0) {
#pragma unroll
      for (int nt = 0; nt < 8; ++nt) {
        int col = nt * 16 + lm;
        atomicAdd(&sred[col], ss[nt]);
        atomicAdd(&sred[128 + col], qq[nt]);
      }
    }
    __syncthreads();
    if (tid < 256) atomicAdd(&stats[tid], sred[tid]);
  }
}

// ---------------- BatchNorm apply (bf16 in-place) ----------------

__global__ void bnb_kernel(ushort* __restrict__ buf, const float* __restrict__ stats,
                           const float* __restrict__ gamma, const float* __restrict__ beta,
                           int n, int act /*0=relu,1=sigmoid*/) {
  int i8 = blockIdx.x * blockDim.x + threadIdx.x;
  if (i8 >= n * 16) return;
  int c0 = (i8 & 15) * 8;
  uint4 v = ((const uint4*)buf)[i8];
  float x[8] = {blo(v.x), bhi(v.x), blo(v.y), bhi(v.y),
                blo(v.z), bhi(v.z), blo(v.w), bhi(v.w)};
  float inv_n = 1.0f / (float)n;
#pragma unroll
  for (int d = 0; d < 8; ++d) {
    int c = c0 + d;
    float mu = stats[c] * inv_n;
    float var = stats[128 + c] * inv_n - mu * mu;
    float y = (x[d] - mu) * rsqrtf(var + 1e-5f) * gamma[c] + beta[c];
    x[d] = (act == 0) ? fmaxf(y, 0.f) : 1.0f / (1.0f + expf(-y));
  }
  uint4 o;
  o.x = pack2(x[0], x[1]); o.y = pack2(x[2], x[3]);
  o.z = pack2(x[4], x[5]); o.w = pack2(x[6], x[7]);
  ((uint4*)buf)[i8] = o;
}

// ---------------- classifier: relu([Hg|Hp]) @ Wc^T + bc (bf16 acts, f32 weights) ----

__global__ __launch_bounds__(256) void cls_kernel(
    const ushort* __restrict__ A, const ushort* __restrict__ B,
    const float* __restrict__ Wc, const float* __restrict__ bias,
    float* __restrict__ C, int M) {
  constexpr int BK = 32, BN = 48, CPT = 3;
  const int K = 128, WS = 256, NC = OUTC;
  __shared__ float As[BK][128 + 4];
  __shared__ float Ws[BK][BN + 1];
  const int tid = threadIdx.x;
  const int tx = tid & 15, ty = tid >> 4;
  const int mbase = blockIdx.x * 128;
  float acc[8][CPT];
#pragma unroll
  for (int i = 0; i < 8; ++i)
#pragma unroll
    for (int j = 0; j < CPT; ++j) acc[i][j] = 0.0f;

  for (int part = 0; part < 2; ++part) {
    const ushort* Ap = (part == 0) ? A : B;
    for (int k0 = 0; k0 < K; k0 += BK) {
      __syncthreads();
#pragma unroll
      for (int r = 0; r < 4; ++r) {
        int f = tid + 256 * r;
        int m = f >> 3, q = f & 7;
        int gm = mbase + m;
        float4 val = make_float4(0.f, 0.f, 0.f, 0.f);
        if (gm < M) {
          ushort4 t = *(const ushort4*)(Ap + (size_t)gm * K + k0 + q * 4);
          val.x = fmaxf(blo(t.x), 0.f); val.y = fmaxf(blo(t.y), 0.f);
          val.z = fmaxf(blo(t.z), 0.f); val.w = fmaxf(blo(t.w), 0.f);
        }
        As[q * 4 + 0][m] = val.x; As[q * 4 + 1][m] = val.y;
        As[q * 4 + 2][m] = val.z; As[q * 4 + 3][m] = val.w;
      }
      for (int f = tid; f < BN * 8; f += 256) {
        int c = f >> 3, q = f & 7;
        float4 wv = make_float4(0.f, 0.f, 0.f, 0.f);
        if (c < NC) wv = *(const float4*)(Wc + (size_t)c * WS + part * 128 + k0 + q * 4);
        Ws[q * 4 + 0][c] = wv.x; Ws[q * 4 + 1][c] = wv.y;
        Ws[q * 4 + 2][c] = wv.z; Ws[q * 4 + 3][c] = wv.w;
      }
      __syncthreads();
#pragma unroll 4
      for (int k = 0; k < BK; ++k) {
        float4 a0 = *(const float4*)&As[k][ty * 8];
        float4 a1 = *(const float4*)&As[k][ty * 8 + 4];
        float a[8] = {a0.x, a0.y, a0.z, a0.w, a1.x, a1.y, a1.z, a1.w};
        float wv[CPT];
#pragma unroll
        for (int j = 0; j < CPT; ++j) wv[j] = Ws[k][tx + 16 * j];
#pragma unroll
        for (int i = 0; i < 8; ++i)
#pragma unroll
          for (int j = 0; j < CPT; ++j) acc[i][j] += a[i] * wv[j];
      }
    }
  }
#pragma unroll
  for (int i = 0; i < 8; ++i) {
    int gm = mbase + ty * 8 + i;
    if (gm >= M) continue;
#pragma unroll
    for (int j = 0; j < CPT; ++j) {
      int c = tx + 16 * j;
      if (c < NC) C[(size_t)gm * NC + c] = acc[i][j] + bias[c];
    }
  }
}

// ---------------- log_softmax over 40 cols, wave per node ----------------

__global__ void logsoftmax_kernel(float* __restrict__ logits, int n) {
  int v = (blockIdx.x * blockDim.x + threadIdx.x) >> 6;
  int lane = threadIdx.x & 63;
  if (v >= n) return;
  float x = (lane < OUTC) ? logits[(size_t)v * OUTC + lane] : -3.4e38f;
  float m = x;
#pragma unroll
  for (int o = 32; o > 0; o >>= 1) m = fmaxf(m, __shfl_xor(m, o));
  float e = (lane < OUTC) ? expf(x - m) : 0.f;
  float s = e;
#pragma unroll
  for (int o = 32; o > 0; o >>= 1) s += __shfl_xor(s, o);
  if (lane < OUTC) logits[(size_t)v * OUTC + lane] = x - m - logf(s);
}

// ---------------- launch ----------------

extern "C" void kernel_launch(void* const* d_in, const int* in_sizes, int n_in,
                              void* d_out, int out_size, void* d_ws, size_t ws_size,
                              hipStream_t stream) {
  const float* x       = (const float*)d_in[0];
  const float* alpha   = (const float*)d_in[1];
  const int*   eidx    = (const int*)d_in[2];
  const float* sage_Wl = (const float*)d_in[3];
  const float* sage_bl = (const float*)d_in[4];
  const float* sage_Wr = (const float*)d_in[5];
  const float* sage_g  = (const float*)d_in[6];
  const float* sage_b  = (const float*)d_in[7];
  const float* W0 = (const float*)d_in[8];
  const float* b0 = (const float*)d_in[9];
  const float* W1 = (const float*)d_in[10];
  const float* b1 = (const float*)d_in[11];
  const float* W2 = (const float*)d_in[12];
  const float* b2 = (const float*)d_in[13];
  const float* mg = (const float*)d_in[14];
  const float* mb = (const float*)d_in[15];
  const float* Wc = (const float*)d_in[16];
  const float* bc = (const float*)d_in[17];
  const float* temp = (const float*)d_in[18];
  float* out = (float*)d_out;

  const int n = in_sizes[0] / HID;  // 100000
  const int e = in_sizes[2] / 2;    // 1600000
  const int* src = eidx;
  const int* tgt = eidx + e;

  const int nbk = (n + 511) >> 9;          // buckets of 512 nodes
  const int glen = nbk * PB;               // bucket table entries
  const int chunk = (e + PB - 1) / PB;     // edges per binning block

  // workspace layout (bf16 buffers first: 16B aligned)
  char* p = (char*)d_ws;
  ushort* xb     = (ushort*)p; p += (size_t)n * HID * 2;   // alias: hgnn
  ushort* hb     = (ushort*)p; p += (size_t)n * HID * 2;   // alias: anb (n*64 <= n*128)
  ushort* aggb   = (ushort*)p; p += (size_t)n * HID * 2;   // alias: ab (alpha bf16)
  ushort* hproto = (ushort*)p; p += (size_t)n * HID * 2;   // alias: ebuf (e*4 <= n*256)
  ushort* wb     = (ushort*)p; p += (size_t)WTOT * 2;
  float* stats = (float*)p; p += 1024 * 4;
  int* rowptr = (int*)p; p += ((size_t)n + 1) * 4;
  int* csr    = (int*)p; p += (size_t)e * 4;
  int* G      = (int*)p; p += (size_t)glen * 4;
  int* Gs     = (int*)p; p += (size_t)glen * 4;
  int* blks   = (int*)p;
  ushort* ab   = aggb;
  ushort* hgnn = xb;
  ushort* anb  = hb;
  int*    ebuf = (int*)hproto;
  ushort* Wlb = wb, *Wrb = wb + 49152, *W0b = wb + 98304, *W1b = wb + 106496, *W2b = wb + 122880;

  const int T = 256;
  const int nb_scan = (glen + SCAN_ELEMS - 1) / SCAN_ELEMS;

  // ---- init + converts ----
  init_kernel<<<4, T, 0, stream>>>(stats);
  cvt_kernel<<<(n * (HID / 4) + T - 1) / T, T, 0, stream>>>(x, xb, n * (HID / 4));
  cvt_kernel<<<(n * 16 + T - 1) / T, T, 0, stream>>>(alpha, ab, n * 16);
  cvtw_kernel<<<(WTOT / 4 + T - 1) / T, T, 0, stream>>>(sage_Wl, sage_Wr, W0, W1, W2, wb);
  anorm_kernel<<<(int)(((size_t)n * 16 + T - 1) / T), T, 0, stream>>>(alpha, anb, n);

  // ---- bucketed CSR build ----
  binA_kernel<<<PB, T, 0, stream>>>(tgt, G, e, chunk, nbk);
  scan1_kernel<<<nb_scan, SCAN_T, 0, stream>>>(G, Gs, blks, glen);
  scan2_kernel<<<1, SCAN_T, 0, stream>>>(blks, nb_scan);
  scan3g_kernel<<<(glen + T - 1) / T, T, 0, stream>>>(Gs, blks, glen);
  binB_kernel<<<PB, T, 0, stream>>>(src, tgt, Gs, ebuf, e, chunk, nbk);
  binC_kernel<<<nbk, T, 0, stream>>>(ebuf, Gs, rowptr, csr, n, e, nbk);

  // ---- gate (pull, fused sigmoid) ----
  gate_pull_kernel<<<(int)(((size_t)n * 8 + T - 1) / T), T, 0, stream>>>(
      anb, rowptr, csr, temp, out + (size_t)n * OUTC, n);

  const int gLin = (n + 127) / 128;
  const int gElem = (n * 16 + T - 1) / T;

  // ---- Proto MLP (hb free after gate_pull consumed anb) ----
  mlin_kernel<1, true><<<gLin, T, 0, stream>>>(ab, nullptr, 64, W0b, nullptr, b0, hb, stats + 512, n);
  bnb_kernel<<<gElem, T, 0, stream>>>(hb, stats + 512, mg, mb, n, 1);
  mlin_kernel<1, true><<<gLin, T, 0, stream>>>(hb, nullptr, 128, W1b, nullptr, b1, hb, stats + 768, n);
  bnb_kernel<<<gElem, T, 0, stream>>>(hb, stats + 768, mg + HID, mb + HID, n, 1);
  mlin_kernel<1, false><<<gLin, T, 0, stream>>>(hb, nullptr, 128, W2b, nullptr, b2, hproto, nullptr, n);

  // ---- SAGE ----
  agg_b_kernel<<<gElem, T, 0, stream>>>(xb, rowptr, csr, aggb, n);
  mlin_kernel<2, true><<<gLin, T, 0, stream>>>(aggb, xb, 128, Wlb, Wrb, sage_bl, hb, stats + 0, n);
  bnb_kernel<<<gElem, T, 0, stream>>>(hb, stats + 0, sage_g, sage_b, n, 0);
  agg_b_kernel<<<gElem, T, 0, stream>>>(hb, rowptr, csr, aggb, n);
  mlin_kernel<2, true><<<gLin, T, 0, stream>>>(aggb, hb, 128, Wlb + 16384, Wrb + 16384,
                                               sage_bl + HID, hb, stats + 256, n);
  bnb_kernel<<<gElem, T, 0, stream>>>(hb, stats + 256, sage_g + HID, sage_b + HID, n, 0);
  agg_b_kernel<<<gElem, T, 0, stream>>>(hb, rowptr, csr, aggb, n);
  mlin_kernel<2, false><<<gLin, T, 0, stream>>>(aggb, hb, 128, Wlb + 32768, Wrb + 32768,
                                                sage_bl + 2 * HID, hgnn, nullptr, n);

  // ---- classifier + log_softmax ----
  cls_kernel<<<gLin, T, 0, stream>>>(hgnn, hproto, Wc, bc, out, n);
  logsoftmax_kernel<<<(int)(((size_t)n * 64 + T - 1) / T), T, 0, stream>>>(out, n);
}

// Round 5
// 826.765 us; speedup vs baseline: 2.0921x; 1.3849x over previous
//
#include <hip/hip_runtime.h>
#include <cstdint>
#include <cstddef>

#define HID 128
#define OUTC 40
#define WTOT 139264  // Wl 49152 | Wr 49152 | W0 8192 | W1 16384 | W2 16384
#define PB 200       // blocks for edge-binning passes
#define NBK_MAX 256  // max buckets (512 nodes each)

typedef __attribute__((ext_vector_type(8))) short short8;
typedef __attribute__((ext_vector_type(4))) float floatx4;

__device__ __forceinline__ unsigned short f2b(float f) {
  unsigned int u = __float_as_uint(f);
  unsigned int r = u + 0x7FFFu + ((u >> 16) & 1u);
  return (unsigned short)(r >> 16);
}
__device__ __forceinline__ float blo(unsigned int u) { return __uint_as_float(u << 16); }
__device__ __forceinline__ float bhi(unsigned int u) { return __uint_as_float(u & 0xFFFF0000u); }
__device__ __forceinline__ unsigned int pack2(float a, float b) {
  return (unsigned int)f2b(a) | ((unsigned int)f2b(b) << 16);
}

__device__ __forceinline__ void async_cp16(const ushort* g, ushort* l) {
  __builtin_amdgcn_global_load_lds((const __attribute__((address_space(1))) void*)g,
                                   (__attribute__((address_space(3))) void*)l, 16, 0, 0);
}

// ---------------- small utility kernels ----------------

__global__ void init_kernel(float* __restrict__ stats) {
  int idx = blockIdx.x * blockDim.x + threadIdx.x;
  if (idx < 1024) stats[idx] = 0.0f;
}

__global__ void cvt_kernel(const float* __restrict__ in, ushort* __restrict__ out, int n4) {
  int i = blockIdx.x * blockDim.x + threadIdx.x;
  if (i >= n4) return;
  float4 v = ((const float4*)in)[i];
  ushort4 o;
  o.x = f2b(v.x); o.y = f2b(v.y); o.z = f2b(v.z); o.w = f2b(v.w);
  ((ushort4*)out)[i] = o;
}

// weights: [Wl 49152][Wr 49152][W0 8192][W1 16384][W2 16384] = 139264 elems
__global__ void cvtw_kernel(const float* __restrict__ Wl, const float* __restrict__ Wr,
                            const float* __restrict__ W0, const float* __restrict__ W1,
                            const float* __restrict__ W2, ushort* __restrict__ wb) {
  int e4 = (blockIdx.x * blockDim.x + threadIdx.x) * 4;
  if (e4 >= WTOT) return;
  const float* s; int off;
  if (e4 < 49152)       { s = Wl; off = 0; }
  else if (e4 < 98304)  { s = Wr; off = 49152; }
  else if (e4 < 106496) { s = W0; off = 98304; }
  else if (e4 < 122880) { s = W1; off = 106496; }
  else                  { s = W2; off = 122880; }
  float4 v = *(const float4*)(s + (e4 - off));
  ushort4 o;
  o.x = f2b(v.x); o.y = f2b(v.y); o.z = f2b(v.z); o.w = f2b(v.w);
  *(ushort4*)(wb + e4) = o;
}

// normalized alpha -> bf16 (an = alpha / max(||alpha||, 1e-12))
__global__ void anorm_kernel(const float* __restrict__ alpha, ushort* __restrict__ anb, int n) {
  int g = (blockIdx.x * blockDim.x + threadIdx.x) >> 4;  // 16 lanes/node
  int lane = threadIdx.x & 15;
  if (g >= n) return;
  const float4 a = *(const float4*)(alpha + (size_t)g * 64 + lane * 4);
  float d = a.x * a.x + a.y * a.y + a.z * a.z + a.w * a.w;
  d += __shfl_xor(d, 1); d += __shfl_xor(d, 2);
  d += __shfl_xor(d, 4); d += __shfl_xor(d, 8);
  float r = 1.0f / fmaxf(sqrtf(d), 1e-12f);
  ushort4 o;
  o.x = f2b(a.x * r); o.y = f2b(a.y * r); o.z = f2b(a.z * r); o.w = f2b(a.w * r);
  *(ushort4*)(anb + (size_t)g * 64 + lane * 4) = o;
}

// ---------------- exclusive scan (generic, for the bucket table) ----------------

#define SCAN_T 256
#define SCAN_VPT 8
#define SCAN_ELEMS 2048

__global__ void scan1_kernel(const int* __restrict__ cnt, int* __restrict__ outp,
                             int* __restrict__ blksum, int n) {
  __shared__ int sh[SCAN_T];
  int t = threadIdx.x;
  int base = blockIdx.x * SCAN_ELEMS + t * SCAN_VPT;
  int v[SCAN_VPT];
  int s = 0;
#pragma unroll
  for (int i = 0; i < SCAN_VPT; ++i) {
    int idx = base + i;
    v[i] = (idx < n) ? cnt[idx] : 0;
    s += v[i];
  }
  sh[t] = s;
  __syncthreads();
  for (int d = 1; d < SCAN_T; d <<= 1) {
    int add = (t >= d) ? sh[t - d] : 0;
    __syncthreads();
    sh[t] += add;
    __syncthreads();
  }
  int p = sh[t] - s;
#pragma unroll
  for (int i = 0; i < SCAN_VPT; ++i) {
    int idx = base + i;
    if (idx < n) outp[idx] = p;
    p += v[i];
  }
  if (t == SCAN_T - 1) blksum[blockIdx.x] = sh[t];
}

__global__ void scan2_kernel(int* __restrict__ blk, int nb) {
  __shared__ int sh[SCAN_T];
  int t = threadIdx.x;
  int s = (t < nb) ? blk[t] : 0;
  sh[t] = s;
  __syncthreads();
  for (int d = 1; d < SCAN_T; d <<= 1) {
    int add = (t >= d) ? sh[t - d] : 0;
    __syncthreads();
    sh[t] += add;
    __syncthreads();
  }
  if (t < nb) blk[t] = sh[t] - s;
}

__global__ void scan3g_kernel(int* __restrict__ outp, const int* __restrict__ blkoff, int n) {
  int idx = blockIdx.x * blockDim.x + threadIdx.x;
  if (idx < n) outp[idx] += blkoff[idx / SCAN_ELEMS];
}

// ---------------- bucketed CSR build (no global atomics, coalesced-ish writes) ----

__global__ void binA_kernel(const int* __restrict__ tgt, int* __restrict__ G,
                            int e, int chunk, int nbk) {
  __shared__ int hist[NBK_MAX];
  int tid = threadIdx.x;
  for (int b = tid; b < nbk; b += 256) hist[b] = 0;
  __syncthreads();
  int i0 = blockIdx.x * chunk;
  int i1 = min(e, i0 + chunk);
  for (int j = i0 + tid; j < i1; j += 256) atomicAdd(&hist[tgt[j] >> 9], 1);
  __syncthreads();
  for (int b = tid; b < nbk; b += 256) G[b * PB + blockIdx.x] = hist[b];
}

__global__ void binB_kernel(const int* __restrict__ src, const int* __restrict__ tgt,
                            const int* __restrict__ Gs, int* __restrict__ ebuf,
                            int e, int chunk, int nbk) {
  __shared__ int cur[NBK_MAX];
  int tid = threadIdx.x;
  for (int b = tid; b < nbk; b += 256) cur[b] = Gs[b * PB + blockIdx.x];
  __syncthreads();
  int i0 = blockIdx.x * chunk;
  int i1 = min(e, i0 + chunk);
  for (int j = i0 + tid; j < i1; j += 256) {
    int t = tgt[j];
    int pos = atomicAdd(&cur[t >> 9], 1);
    ebuf[pos] = ((t & 511) << 17) | src[j];
  }
}

__global__ void binC_kernel(const int* __restrict__ ebuf, const int* __restrict__ Gs,
                            int* __restrict__ rowptr, int* __restrict__ csr,
                            int n, int e, int nbk) {
  __shared__ int hist[512];
  __shared__ int scanbuf[256];
  int b = blockIdx.x, tid = threadIdx.x;
  int seg0 = Gs[b * PB];
  int seg1 = (b + 1 < nbk) ? Gs[(b + 1) * PB] : e;
  hist[tid] = 0; hist[tid + 256] = 0;
  __syncthreads();
  for (int j = seg0 + tid; j < seg1; j += 256)
    atomicAdd(&hist[ebuf[j] >> 17], 1);
  __syncthreads();
  int a0 = hist[2 * tid], a1 = hist[2 * tid + 1];
  int s = a0 + a1;
  scanbuf[tid] = s;
  __syncthreads();
  for (int d = 1; d < 256; d <<= 1) {
    int add = (tid >= d) ? scanbuf[tid - d] : 0;
    __syncthreads();
    scanbuf[tid] += add;
    __syncthreads();
  }
  int ex = scanbuf[tid] - s;
  hist[2 * tid] = ex;
  hist[2 * tid + 1] = ex + a0;
  int node0 = b * 512 + 2 * tid;
  if (node0 < n) rowptr[node0] = seg0 + ex;
  if (node0 + 1 < n) rowptr[node0 + 1] = seg0 + ex + a0;
  __syncthreads();
  for (int j = seg0 + tid; j < seg1; j += 256) {
    int val = ebuf[j];
    int pos = atomicAdd(&hist[val >> 17], 1);
    csr[seg0 + pos] = val & 0x1FFFF;
  }
  if (b == nbk - 1 && tid == 0) rowptr[n] = e;
}

// ---------------- gate: pull-based, fused sigmoid (no atomics) ----------------

__global__ void gate_pull_kernel(const ushort* __restrict__ anb, const int* __restrict__ rowptr,
                                 const int* __restrict__ csr, const float* __restrict__ temp,
                                 float* __restrict__ out, int n) {
  int g = (blockIdx.x * blockDim.x + threadIdx.x) >> 3;  // 8 lanes/node
  int lane = threadIdx.x & 7;
  if (g >= n) return;
  uint4 av = *(const uint4*)(anb + (size_t)g * 64 + lane * 8);
  int beg = rowptr[g], end = rowptr[g + 1];
  float acc = 0.f;
  int j = beg;
  for (; j + 1 < end; j += 2) {
    int u0 = csr[j], u1 = csr[j + 1];
    uint4 b0 = *(const uint4*)(anb + (size_t)u0 * 64 + lane * 8);
    uint4 b1 = *(const uint4*)(anb + (size_t)u1 * 64 + lane * 8);
    acc += blo(av.x) * (blo(b0.x) + blo(b1.x)) + bhi(av.x) * (bhi(b0.x) + bhi(b1.x))
         + blo(av.y) * (blo(b0.y) + blo(b1.y)) + bhi(av.y) * (bhi(b0.y) + bhi(b1.y))
         + blo(av.z) * (blo(b0.z) + blo(b1.z)) + bhi(av.z) * (bhi(b0.z) + bhi(b1.z))
         + blo(av.w) * (blo(b0.w) + blo(b1.w)) + bhi(av.w) * (bhi(b0.w) + bhi(b1.w));
  }
  if (j < end) {
    int u0 = csr[j];
    uint4 b0 = *(const uint4*)(anb + (size_t)u0 * 64 + lane * 8);
    acc += blo(av.x) * blo(b0.x) + bhi(av.x) * bhi(b0.x)
         + blo(av.y) * blo(b0.y) + bhi(av.y) * bhi(b0.y)
         + blo(av.z) * blo(b0.z) + bhi(av.z) * bhi(b0.z)
         + blo(av.w) * blo(b0.w) + bhi(av.w) * bhi(b0.w);
  }
  acc += __shfl_xor(acc, 1); acc += __shfl_xor(acc, 2); acc += __shfl_xor(acc, 4);
  if (lane == 0) {
    float m = (1.0f + acc) / (float)(end - beg + 1);  // self-loop dot = 1
    out[g] = 1.0f / (1.0f + expf(-temp[0] * m));
  }
}

// ---------------- SAGE mean aggregation (bf16 in/out, f32 accumulate) ----------------

__global__ void agg_b_kernel(const ushort* __restrict__ h, const int* __restrict__ rowptr,
                             const int* __restrict__ csr, ushort* __restrict__ outb, int n) {
  int g = (blockIdx.x * blockDim.x + threadIdx.x) >> 4;  // 16 lanes / node
  int lane = threadIdx.x & 15;
  if (g >= n) return;
  int beg = rowptr[g], end = rowptr[g + 1];
  float a0=0,a1=0,a2=0,a3=0,a4=0,a5=0,a6=0,a7=0;
  int j = beg;
  for (; j + 3 < end; j += 4) {
    int u0 = csr[j], u1 = csr[j + 1], u2 = csr[j + 2], u3 = csr[j + 3];
    uint4 v0 = *(const uint4*)(h + (size_t)u0 * HID + lane * 8);
    uint4 v1 = *(const uint4*)(h + (size_t)u1 * HID + lane * 8);
    uint4 v2 = *(const uint4*)(h + (size_t)u2 * HID + lane * 8);
    uint4 v3 = *(const uint4*)(h + (size_t)u3 * HID + lane * 8);
    a0 += (blo(v0.x) + blo(v1.x)) + (blo(v2.x) + blo(v3.x));
    a1 += (bhi(v0.x) + bhi(v1.x)) + (bhi(v2.x) + bhi(v3.x));
    a2 += (blo(v0.y) + blo(v1.y)) + (blo(v2.y) + blo(v3.y));
    a3 += (bhi(v0.y) + bhi(v1.y)) + (bhi(v2.y) + bhi(v3.y));
    a4 += (blo(v0.z) + blo(v1.z)) + (blo(v2.z) + blo(v3.z));
    a5 += (bhi(v0.z) + bhi(v1.z)) + (bhi(v2.z) + bhi(v3.z));
    a6 += (blo(v0.w) + blo(v1.w)) + (blo(v2.w) + blo(v3.w));
    a7 += (bhi(v0.w) + bhi(v1.w)) + (bhi(v2.w) + bhi(v3.w));
  }
  for (; j < end; ++j) {
    int u0 = csr[j];
    uint4 v0 = *(const uint4*)(h + (size_t)u0 * HID + lane * 8);
    a0 += blo(v0.x); a1 += bhi(v0.x); a2 += blo(v0.y); a3 += bhi(v0.y);
    a4 += blo(v0.z); a5 += bhi(v0.z); a6 += blo(v0.w); a7 += bhi(v0.w);
  }
  float r = (end > beg) ? 1.0f / (float)(end - beg) : 0.0f;
  uint4 o;
  o.x = pack2(a0 * r, a1 * r); o.y = pack2(a2 * r, a3 * r);
  o.z = pack2(a4 * r, a5 * r); o.w = pack2(a6 * r, a7 * r);
  *(uint4*)(outb + (size_t)g * HID + lane * 8) = o;
}

// ---------------- MFMA linear: C = A1@W1^T (+ A2@W2^T) + bias, bf16 in, bf16 out ----

template <int NPARTS, bool STATS>
__global__ __launch_bounds__(256) void mlin_kernel(
    const ushort* __restrict__ A1, const ushort* __restrict__ A2, int K,
    const ushort* __restrict__ W1, const ushort* __restrict__ W2,
    const float* __restrict__ bias, ushort* __restrict__ C,
    float* __restrict__ stats, int M) {
  __shared__ ushort As[128 * 32];
  __shared__ ushort Bs[128 * 32];
  const int tid = threadIdx.x;
  const int w = tid >> 6, l = tid & 63;
  const int mbase = blockIdx.x * 128;
  const int lm = l & 15, lq = l >> 4;
  floatx4 acc[2][8];
#pragma unroll
  for (int mt = 0; mt < 2; ++mt)
#pragma unroll
    for (int nt = 0; nt < 8; ++nt) {
      floatx4 z = {0.f, 0.f, 0.f, 0.f};
      acc[mt][nt] = z;
    }

  for (int part = 0; part < NPARTS; ++part) {
    const ushort* Ap = part ? A2 : A1;
    const ushort* Wp = part ? W2 : W1;
    for (int k0 = 0; k0 < K; k0 += 32) {
#pragma unroll
      for (int i = 0; i < 2; ++i) {
        int s = w * 2 + i;
        int rt = s * 16 + (l >> 2);
        int q = (l & 3) ^ ((rt >> 1) & 3);
        int grow = mbase + rt; grow = grow < M ? grow : M - 1;
        async_cp16(Ap + (size_t)grow * K + k0 + q * 8, &As[s * 512]);
        async_cp16(Wp + (size_t)rt * K + k0 + q * 8, &Bs[s * 512]);
      }
      __syncthreads();
      short8 b[8];
#pragma unroll
      for (int nt = 0; nt < 8; ++nt) {
        int row = nt * 16 + lm;
        int q = lq ^ ((row >> 1) & 3);
        b[nt] = *(const short8*)&Bs[row * 32 + q * 8];
      }
#pragma unroll
      for (int mt = 0; mt < 2; ++mt) {
        int row = (w * 2 + mt) * 16 + lm;
        int q = lq ^ ((row >> 1) & 3);
        short8 a = *(const short8*)&As[row * 32 + q * 8];
#pragma unroll
        for (int nt = 0; nt < 8; ++nt)
          acc[mt][nt] = __builtin_amdgcn_mfma_f32_16x16x32_bf16(a, b[nt], acc[mt][nt], 0, 0, 0);
      }
      __syncthreads();
    }
  }

  // epilogue: C/D layout col = lane&15, row = (lane>>4)*4 + reg
  float ss[8], qq[8];
#pragma unroll
  for (int nt = 0; nt < 8; ++nt) { ss[nt] = 0.f; qq[nt] = 0.f; }
#pragma unroll
  for (int nt = 0; nt < 8; ++nt) {
    int col = nt * 16 + lm;
    float bv = bias[col];
#pragma unroll
    for (int mt = 0; mt < 2; ++mt) {
      int rbase = mbase + (w * 2 + mt) * 16 + lq * 4;
#pragma unroll
      for (int r = 0; r < 4; ++r) {
        int grow = rbase + r;
        if (grow < M) {
          float val = acc[mt][nt][r] + bv;
          C[(size_t)grow * 128 + col] = f2b(val);
          if (STATS) { ss[nt] += val; qq[nt] += val * val; }
        }
      }
    }
  }
  if (STATS) {
    float* sred = (float*)As;  // safe: past last barrier, no more tile reads
    if (tid < 256) sred[tid] = 0.f;
    __syncthreads();
#pragma unroll
    for (int nt = 0; nt < 8; ++nt) {
      ss[nt] += __shfl_xor(ss[nt], 16); ss[nt] += __shfl_xor(ss[nt], 32);
      qq[nt] += __shfl_xor(qq[nt], 16); qq[nt] += __shfl_xor(qq[nt], 32);
    }
    if (lq == 0) {
#pragma unroll
      for (int nt = 0; nt < 8; ++nt) {
        int col = nt * 16 + lm;
        atomicAdd(&sred[col], ss[nt]);
        atomicAdd(&sred[128 + col], qq[nt]);
      }
    }
    __syncthreads();
    if (tid < 256) atomicAdd(&stats[tid], sred[tid]);
  }
}

// ---------------- BatchNorm apply (bf16 in-place, latency-optimized) ----------------
// Per-thread column set is grid-stride-invariant (stride % 16 == 0), so the 8
// scale/shift pairs are computed ONCE per thread, then the loop is pure stream.

template <int ACT>  // 0=relu, 1=sigmoid
__global__ __launch_bounds__(256) void bnb_kernel(
    ushort* __restrict__ buf, const float* __restrict__ stats,
    const float* __restrict__ gamma, const float* __restrict__ beta, int n) {
  const int S = gridDim.x * 256;  // multiple of 16
  int idx = blockIdx.x * 256 + threadIdx.x;
  const int c0 = (idx & 15) * 8;
  const float inv_n = 1.0f / (float)n;
  float sc[8], sh[8];
#pragma unroll
  for (int d = 0; d < 8; ++d) {
    int c = c0 + d;
    float mu = stats[c] * inv_n;
    float var = stats[128 + c] * inv_n - mu * mu;
    float s = rsqrtf(var + 1e-5f) * gamma[c];
    sc[d] = s;
    sh[d] = beta[c] - mu * s;
  }
  const int n16 = n * 16;
  for (; idx < n16; idx += S) {
    uint4 v = ((const uint4*)buf)[idx];
    float x[8] = {blo(v.x), bhi(v.x), blo(v.y), bhi(v.y),
                  blo(v.z), bhi(v.z), blo(v.w), bhi(v.w)};
#pragma unroll
    for (int d = 0; d < 8; ++d) {
      float y = x[d] * sc[d] + sh[d];
      x[d] = (ACT == 0) ? fmaxf(y, 0.f) : 1.0f / (1.0f + expf(-y));
    }
    uint4 o;
    o.x = pack2(x[0], x[1]); o.y = pack2(x[2], x[3]);
    o.z = pack2(x[4], x[5]); o.w = pack2(x[6], x[7]);
    ((uint4*)buf)[idx] = o;
  }
}

// ---------------- classifier + fused log_softmax ----------------
// relu([Hg|Hp]) @ Wc^T + bc, then log_softmax over the 40 cols in-register.
// Row gm is owned by the 16 lanes {ty*16..ty*16+15} of one wave -> shfl reduce.

__global__ __launch_bounds__(256) void cls_kernel(
    const ushort* __restrict__ A, const ushort* __restrict__ B,
    const float* __restrict__ Wc, const float* __restrict__ bias,
    float* __restrict__ C, int M) {
  constexpr int BK = 32, BN = 48, CPT = 3;
  const int K = 128, WS = 256, NC = OUTC;
  __shared__ float As[BK][128 + 4];
  __shared__ float Ws[BK][BN + 1];
  const int tid = threadIdx.x;
  const int tx = tid & 15, ty = tid >> 4;
  const int mbase = blockIdx.x * 128;
  float acc[8][CPT];
#pragma unroll
  for (int i = 0; i < 8; ++i)
#pragma unroll
    for (int j = 0; j < CPT; ++j) acc[i][j] = 0.0f;

  for (int part = 0; part < 2; ++part) {
    const ushort* Ap = (part == 0) ? A : B;
    for (int k0 = 0; k0 < K; k0 += BK) {
      __syncthreads();
#pragma unroll
      for (int r = 0; r < 4; ++r) {
        int f = tid + 256 * r;
        int m = f >> 3, q = f & 7;
        int gm = mbase + m;
        float4 val = make_float4(0.f, 0.f, 0.f, 0.f);
        if (gm < M) {
          ushort4 t = *(const ushort4*)(Ap + (size_t)gm * K + k0 + q * 4);
          val.x = fmaxf(blo(t.x), 0.f); val.y = fmaxf(blo(t.y), 0.f);
          val.z = fmaxf(blo(t.z), 0.f); val.w = fmaxf(blo(t.w), 0.f);
        }
        As[q * 4 + 0][m] = val.x; As[q * 4 + 1][m] = val.y;
        As[q * 4 + 2][m] = val.z; As[q * 4 + 3][m] = val.w;
      }
      for (int f = tid; f < BN * 8; f += 256) {
        int c = f >> 3, q = f & 7;
        float4 wv = make_float4(0.f, 0.f, 0.f, 0.f);
        if (c < NC) wv = *(const float4*)(Wc + (size_t)c * WS + part * 128 + k0 + q * 4);
        Ws[q * 4 + 0][c] = wv.x; Ws[q * 4 + 1][c] = wv.y;
        Ws[q * 4 + 2][c] = wv.z; Ws[q * 4 + 3][c] = wv.w;
      }
      __syncthreads();
#pragma unroll 4
      for (int k = 0; k < BK; ++k) {
        float4 a0 = *(const float4*)&As[k][ty * 8];
        float4 a1 = *(const float4*)&As[k][ty * 8 + 4];
        float a[8] = {a0.x, a0.y, a0.z, a0.w, a1.x, a1.y, a1.z, a1.w};
        float wv[CPT];
#pragma unroll
        for (int j = 0; j < CPT; ++j) wv[j] = Ws[k][tx + 16 * j];
#pragma unroll
        for (int i = 0; i < 8; ++i)
#pragma unroll
          for (int j = 0; j < CPT; ++j) acc[i][j] += a[i] * wv[j];
      }
    }
  }
  // fused epilogue: bias + log_softmax over 40 cols (lanes tx=0..15 hold 3 cols)
  float b0 = bias[tx], b1 = bias[tx + 16];
  float b2 = (tx < 8) ? bias[tx + 32] : 0.f;
#pragma unroll
  for (int i = 0; i < 8; ++i) {
    int gm = mbase + ty * 8 + i;
    float v0 = acc[i][0] + b0;
    float v1 = acc[i][1] + b1;
    float v2 = (tx < 8) ? acc[i][2] + b2 : -3.4e38f;
    float m = fmaxf(fmaxf(v0, v1), v2);
    m = fmaxf(m, __shfl_xor(m, 1)); m = fmaxf(m, __shfl_xor(m, 2));
    m = fmaxf(m, __shfl_xor(m, 4)); m = fmaxf(m, __shfl_xor(m, 8));
    float s = expf(v0 - m) + expf(v1 - m) + ((tx < 8) ? expf(v2 - m) : 0.f);
    s += __shfl_xor(s, 1); s += __shfl_xor(s, 2);
    s += __shfl_xor(s, 4); s += __shfl_xor(s, 8);
    float ls = m + logf(s);
    if (gm < M) {
      C[(size_t)gm * NC + tx] = v0 - ls;
      C[(size_t)gm * NC + tx + 16] = v1 - ls;
      if (tx < 8) C[(size_t)gm * NC + tx + 32] = v2 - ls;
    }
  }
}

// ---------------- launch ----------------

extern "C" void kernel_launch(void* const* d_in, const int* in_sizes, int n_in,
                              void* d_out, int out_size, void* d_ws, size_t ws_size,
                              hipStream_t stream) {
  const float* x       = (const float*)d_in[0];
  const float* alpha   = (const float*)d_in[1];
  const int*   eidx    = (const int*)d_in[2];
  const float* sage_Wl = (const float*)d_in[3];
  const float* sage_bl = (const float*)d_in[4];
  const float* sage_Wr = (const float*)d_in[5];
  const float* sage_g  = (const float*)d_in[6];
  const float* sage_b  = (const float*)d_in[7];
  const float* W0 = (const float*)d_in[8];
  const float* b0 = (const float*)d_in[9];
  const float* W1 = (const float*)d_in[10];
  const float* b1 = (const float*)d_in[11];
  const float* W2 = (const float*)d_in[12];
  const float* b2 = (const float*)d_in[13];
  const float* mg = (const float*)d_in[14];
  const float* mb = (const float*)d_in[15];
  const float* Wc = (const float*)d_in[16];
  const float* bc = (const float*)d_in[17];
  const float* temp = (const float*)d_in[18];
  float* out = (float*)d_out;

  const int n = in_sizes[0] / HID;  // 100000
  const int e = in_sizes[2] / 2;    // 1600000
  const int* src = eidx;
  const int* tgt = eidx + e;

  const int nbk = (n + 511) >> 9;
  const int glen = nbk * PB;
  const int chunk = (e + PB - 1) / PB;

  // workspace layout (bf16 buffers first: 16B aligned)
  char* p = (char*)d_ws;
  ushort* xb     = (ushort*)p; p += (size_t)n * HID * 2;   // alias: hgnn
  ushort* hb     = (ushort*)p; p += (size_t)n * HID * 2;   // alias: anb
  ushort* aggb   = (ushort*)p; p += (size_t)n * HID * 2;   // alias: ab
  ushort* hproto = (ushort*)p; p += (size_t)n * HID * 2;   // alias: ebuf
  ushort* wb     = (ushort*)p; p += (size_t)WTOT * 2;
  float* stats = (float*)p; p += 1024 * 4;
  int* rowptr = (int*)p; p += ((size_t)n + 1) * 4;
  int* csr    = (int*)p; p += (size_t)e * 4;
  int* G      = (int*)p; p += (size_t)glen * 4;
  int* Gs     = (int*)p; p += (size_t)glen * 4;
  int* blks   = (int*)p;
  ushort* ab   = aggb;
  ushort* hgnn = xb;
  ushort* anb  = hb;
  int*    ebuf = (int*)hproto;
  ushort* Wlb = wb, *Wrb = wb + 49152, *W0b = wb + 98304, *W1b = wb + 106496, *W2b = wb + 122880;

  const int T = 256;
  const int nb_scan = (glen + SCAN_ELEMS - 1) / SCAN_ELEMS;

  // ---- init + converts ----
  init_kernel<<<4, T, 0, stream>>>(stats);
  cvt_kernel<<<(n * (HID / 4) + T - 1) / T, T, 0, stream>>>(x, xb, n * (HID / 4));
  cvt_kernel<<<(n * 16 + T - 1) / T, T, 0, stream>>>(alpha, ab, n * 16);
  cvtw_kernel<<<(WTOT / 4 + T - 1) / T, T, 0, stream>>>(sage_Wl, sage_Wr, W0, W1, W2, wb);
  anorm_kernel<<<(int)(((size_t)n * 16 + T - 1) / T), T, 0, stream>>>(alpha, anb, n);

  // ---- bucketed CSR build ----
  binA_kernel<<<PB, T, 0, stream>>>(tgt, G, e, chunk, nbk);
  scan1_kernel<<<nb_scan, SCAN_T, 0, stream>>>(G, Gs, blks, glen);
  scan2_kernel<<<1, SCAN_T, 0, stream>>>(blks, nb_scan);
  scan3g_kernel<<<(glen + T - 1) / T, T, 0, stream>>>(Gs, blks, glen);
  binB_kernel<<<PB, T, 0, stream>>>(src, tgt, Gs, ebuf, e, chunk, nbk);
  binC_kernel<<<nbk, T, 0, stream>>>(ebuf, Gs, rowptr, csr, n, e, nbk);

  // ---- gate (pull, fused sigmoid) ----
  gate_pull_kernel<<<(int)(((size_t)n * 8 + T - 1) / T), T, 0, stream>>>(
      anb, rowptr, csr, temp, out + (size_t)n * OUTC, n);

  const int gLin = (n + 127) / 128;
  const int gElem = (n * 16 + T - 1) / T;
  const int gBn = 1024;  // grid-stride; 256*1024 threads, stride % 16 == 0

  // ---- Proto MLP (hb free after gate_pull consumed anb) ----
  mlin_kernel<1, true><<<gLin, T, 0, stream>>>(ab, nullptr, 64, W0b, nullptr, b0, hb, stats + 512, n);
  bnb_kernel<1><<<gBn, T, 0, stream>>>(hb, stats + 512, mg, mb, n);
  mlin_kernel<1, true><<<gLin, T, 0, stream>>>(hb, nullptr, 128, W1b, nullptr, b1, hb, stats + 768, n);
  bnb_kernel<1><<<gBn, T, 0, stream>>>(hb, stats + 768, mg + HID, mb + HID, n);
  mlin_kernel<1, false><<<gLin, T, 0, stream>>>(hb, nullptr, 128, W2b, nullptr, b2, hproto, nullptr, n);

  // ---- SAGE ----
  agg_b_kernel<<<gElem, T, 0, stream>>>(xb, rowptr, csr, aggb, n);
  mlin_kernel<2, true><<<gLin, T, 0, stream>>>(aggb, xb, 128, Wlb, Wrb, sage_bl, hb, stats + 0, n);
  bnb_kernel<0><<<gBn, T, 0, stream>>>(hb, stats + 0, sage_g, sage_b, n);
  agg_b_kernel<<<gElem, T, 0, stream>>>(hb, rowptr, csr, aggb, n);
  mlin_kernel<2, true><<<gLin, T, 0, stream>>>(aggb, hb, 128, Wlb + 16384, Wrb + 16384,
                                               sage_bl + HID, hb, stats + 256, n);
  bnb_kernel<0><<<gBn, T, 0, stream>>>(hb, stats + 256, sage_g + HID, sage_b + HID, n);
  agg_b_kernel<<<gElem, T, 0, stream>>>(hb, rowptr, csr, aggb, n);
  mlin_kernel<2, false><<<gLin, T, 0, stream>>>(aggb, hb, 128, Wlb + 32768, Wrb + 32768,
                                                sage_bl + 2 * HID, hgnn, nullptr, n);

  // ---- classifier (log_softmax fused) ----
  cls_kernel<<<gLin, T, 0, stream>>>(hgnn, hproto, Wc, bc, out, n);
}

// Round 6
// 774.550 us; speedup vs baseline: 2.2332x; 1.0674x over previous
//
#include <hip/hip_runtime.h>
#include <cstdint>
#include <cstddef>

#define HID 128
#define OUTC 40
#define WTOT 139264  // Wl 49152 | Wr 49152 | W0 8192 | W1 16384 | W2 16384
#define PB 200       // blocks for edge-binning passes
#define NBK_MAX 256  // max buckets (512 nodes each)

typedef __attribute__((ext_vector_type(8))) short short8;
typedef __attribute__((ext_vector_type(4))) float floatx4;

__device__ __forceinline__ unsigned short f2b(float f) {
  unsigned int u = __float_as_uint(f);
  unsigned int r = u + 0x7FFFu + ((u >> 16) & 1u);
  return (unsigned short)(r >> 16);
}
__device__ __forceinline__ float blo(unsigned int u) { return __uint_as_float(u << 16); }
__device__ __forceinline__ float bhi(unsigned int u) { return __uint_as_float(u & 0xFFFF0000u); }
__device__ __forceinline__ unsigned int pack2(float a, float b) {
  return (unsigned int)f2b(a) | ((unsigned int)f2b(b) << 16);
}

__device__ __forceinline__ void async_cp16(const ushort* g, ushort* l) {
  __builtin_amdgcn_global_load_lds((const __attribute__((address_space(1))) void*)g,
                                   (__attribute__((address_space(3))) void*)l, 16, 0, 0);
}

// ---------------- small utility kernels ----------------

__global__ void init_kernel(float* __restrict__ stats) {
  int idx = blockIdx.x * blockDim.x + threadIdx.x;
  if (idx < 1024) stats[idx] = 0.0f;
}

__global__ void cvt_kernel(const float* __restrict__ in, ushort* __restrict__ out, int n4) {
  int i = blockIdx.x * blockDim.x + threadIdx.x;
  if (i >= n4) return;
  float4 v = ((const float4*)in)[i];
  ushort4 o;
  o.x = f2b(v.x); o.y = f2b(v.y); o.z = f2b(v.z); o.w = f2b(v.w);
  ((ushort4*)out)[i] = o;
}

// weights: [Wl 49152][Wr 49152][W0 8192][W1 16384][W2 16384] = 139264 elems
__global__ void cvtw_kernel(const float* __restrict__ Wl, const float* __restrict__ Wr,
                            const float* __restrict__ W0, const float* __restrict__ W1,
                            const float* __restrict__ W2, ushort* __restrict__ wb) {
  int e4 = (blockIdx.x * blockDim.x + threadIdx.x) * 4;
  if (e4 >= WTOT) return;
  const float* s; int off;
  if (e4 < 49152)       { s = Wl; off = 0; }
  else if (e4 < 98304)  { s = Wr; off = 49152; }
  else if (e4 < 106496) { s = W0; off = 98304; }
  else if (e4 < 122880) { s = W1; off = 106496; }
  else                  { s = W2; off = 122880; }
  float4 v = *(const float4*)(s + (e4 - off));
  ushort4 o;
  o.x = f2b(v.x); o.y = f2b(v.y); o.z = f2b(v.z); o.w = f2b(v.w);
  *(ushort4*)(wb + e4) = o;
}

// Wc (40x256 f32) -> wcb (48x256 bf16, rows 40..47 zero)
__global__ void cvtwc_kernel(const float* __restrict__ Wc, ushort* __restrict__ wcb) {
  int i4 = blockIdx.x * blockDim.x + threadIdx.x;
  if (i4 >= 48 * 64) return;
  int row = i4 >> 6;
  ushort4 o;
  if (row < 40) {
    float4 v = *(const float4*)(Wc + (size_t)i4 * 4);
    o.x = f2b(v.x); o.y = f2b(v.y); o.z = f2b(v.z); o.w = f2b(v.w);
  } else {
    o.x = 0; o.y = 0; o.z = 0; o.w = 0;
  }
  ((ushort4*)wcb)[i4] = o;
}

// normalized alpha -> bf16 (an = alpha / max(||alpha||, 1e-12))
__global__ void anorm_kernel(const float* __restrict__ alpha, ushort* __restrict__ anb, int n) {
  int g = (blockIdx.x * blockDim.x + threadIdx.x) >> 4;  // 16 lanes/node
  int lane = threadIdx.x & 15;
  if (g >= n) return;
  const float4 a = *(const float4*)(alpha + (size_t)g * 64 + lane * 4);
  float d = a.x * a.x + a.y * a.y + a.z * a.z + a.w * a.w;
  d += __shfl_xor(d, 1); d += __shfl_xor(d, 2);
  d += __shfl_xor(d, 4); d += __shfl_xor(d, 8);
  float r = 1.0f / fmaxf(sqrtf(d), 1e-12f);
  ushort4 o;
  o.x = f2b(a.x * r); o.y = f2b(a.y * r); o.z = f2b(a.z * r); o.w = f2b(a.w * r);
  *(ushort4*)(anb + (size_t)g * 64 + lane * 4) = o;
}

// ---------------- exclusive scan (generic, for the bucket table) ----------------

#define SCAN_T 256
#define SCAN_VPT 8
#define SCAN_ELEMS 2048

__global__ void scan1_kernel(const int* __restrict__ cnt, int* __restrict__ outp,
                             int* __restrict__ blksum, int n) {
  __shared__ int sh[SCAN_T];
  int t = threadIdx.x;
  int base = blockIdx.x * SCAN_ELEMS + t * SCAN_VPT;
  int v[SCAN_VPT];
  int s = 0;
#pragma unroll
  for (int i = 0; i < SCAN_VPT; ++i) {
    int idx = base + i;
    v[i] = (idx < n) ? cnt[idx] : 0;
    s += v[i];
  }
  sh[t] = s;
  __syncthreads();
  for (int d = 1; d < SCAN_T; d <<= 1) {
    int add = (t >= d) ? sh[t - d] : 0;
    __syncthreads();
    sh[t] += add;
    __syncthreads();
  }
  int p = sh[t] - s;
#pragma unroll
  for (int i = 0; i < SCAN_VPT; ++i) {
    int idx = base + i;
    if (idx < n) outp[idx] = p;
    p += v[i];
  }
  if (t == SCAN_T - 1) blksum[blockIdx.x] = sh[t];
}

__global__ void scan2_kernel(int* __restrict__ blk, int nb) {
  __shared__ int sh[SCAN_T];
  int t = threadIdx.x;
  int s = (t < nb) ? blk[t] : 0;
  sh[t] = s;
  __syncthreads();
  for (int d = 1; d < SCAN_T; d <<= 1) {
    int add = (t >= d) ? sh[t - d] : 0;
    __syncthreads();
    sh[t] += add;
    __syncthreads();
  }
  if (t < nb) blk[t] = sh[t] - s;
}

__global__ void scan3g_kernel(int* __restrict__ outp, const int* __restrict__ blkoff, int n) {
  int idx = blockIdx.x * blockDim.x + threadIdx.x;
  if (idx < n) outp[idx] += blkoff[idx / SCAN_ELEMS];
}

// ---------------- bucketed CSR build (no global atomics) ----------------

__global__ void binA_kernel(const int* __restrict__ tgt, int* __restrict__ G,
                            int e, int chunk, int nbk) {
  __shared__ int hist[NBK_MAX];
  int tid = threadIdx.x;
  for (int b = tid; b < nbk; b += 256) hist[b] = 0;
  __syncthreads();
  int i0 = blockIdx.x * chunk;
  int i1 = min(e, i0 + chunk);
  for (int j = i0 + tid; j < i1; j += 256) atomicAdd(&hist[tgt[j] >> 9], 1);
  __syncthreads();
  for (int b = tid; b < nbk; b += 256) G[b * PB + blockIdx.x] = hist[b];
}

__global__ void binB_kernel(const int* __restrict__ src, const int* __restrict__ tgt,
                            const int* __restrict__ Gs, int* __restrict__ ebuf,
                            int e, int chunk, int nbk) {
  __shared__ int cur[NBK_MAX];
  int tid = threadIdx.x;
  for (int b = tid; b < nbk; b += 256) cur[b] = Gs[b * PB + blockIdx.x];
  __syncthreads();
  int i0 = blockIdx.x * chunk;
  int i1 = min(e, i0 + chunk);
  for (int j = i0 + tid; j < i1; j += 256) {
    int t = tgt[j];
    int pos = atomicAdd(&cur[t >> 9], 1);
    ebuf[pos] = ((t & 511) << 17) | src[j];
  }
}

__global__ void binC_kernel(const int* __restrict__ ebuf, const int* __restrict__ Gs,
                            int* __restrict__ rowptr, int* __restrict__ csr,
                            int n, int e, int nbk) {
  __shared__ int hist[512];
  __shared__ int scanbuf[256];
  int b = blockIdx.x, tid = threadIdx.x;
  int seg0 = Gs[b * PB];
  int seg1 = (b + 1 < nbk) ? Gs[(b + 1) * PB] : e;
  hist[tid] = 0; hist[tid + 256] = 0;
  __syncthreads();
  for (int j = seg0 + tid; j < seg1; j += 256)
    atomicAdd(&hist[ebuf[j] >> 17], 1);
  __syncthreads();
  int a0 = hist[2 * tid], a1 = hist[2 * tid + 1];
  int s = a0 + a1;
  scanbuf[tid] = s;
  __syncthreads();
  for (int d = 1; d < 256; d <<= 1) {
    int add = (tid >= d) ? scanbuf[tid - d] : 0;
    __syncthreads();
    scanbuf[tid] += add;
    __syncthreads();
  }
  int ex = scanbuf[tid] - s;
  hist[2 * tid] = ex;
  hist[2 * tid + 1] = ex + a0;
  int node0 = b * 512 + 2 * tid;
  if (node0 < n) rowptr[node0] = seg0 + ex;
  if (node0 + 1 < n) rowptr[node0 + 1] = seg0 + ex + a0;
  __syncthreads();
  for (int j = seg0 + tid; j < seg1; j += 256) {
    int val = ebuf[j];
    int pos = atomicAdd(&hist[val >> 17], 1);
    csr[seg0 + pos] = val & 0x1FFFF;
  }
  if (b == nbk - 1 && tid == 0) rowptr[n] = e;
}

// ---------------- gate: pull-based, fused sigmoid (no atomics) ----------------

__global__ void gate_pull_kernel(const ushort* __restrict__ anb, const int* __restrict__ rowptr,
                                 const int* __restrict__ csr, const float* __restrict__ temp,
                                 float* __restrict__ out, int n) {
  int g = (blockIdx.x * blockDim.x + threadIdx.x) >> 3;  // 8 lanes/node
  int lane = threadIdx.x & 7;
  if (g >= n) return;
  uint4 av = *(const uint4*)(anb + (size_t)g * 64 + lane * 8);
  int beg = rowptr[g], end = rowptr[g + 1];
  float acc = 0.f;
  int j = beg;
  for (; j + 1 < end; j += 2) {
    int u0 = csr[j], u1 = csr[j + 1];
    uint4 b0 = *(const uint4*)(anb + (size_t)u0 * 64 + lane * 8);
    uint4 b1 = *(const uint4*)(anb + (size_t)u1 * 64 + lane * 8);
    acc += blo(av.x) * (blo(b0.x) + blo(b1.x)) + bhi(av.x) * (bhi(b0.x) + bhi(b1.x))
         + blo(av.y) * (blo(b0.y) + blo(b1.y)) + bhi(av.y) * (bhi(b0.y) + bhi(b1.y))
         + blo(av.z) * (blo(b0.z) + blo(b1.z)) + bhi(av.z) * (bhi(b0.z) + bhi(b1.z))
         + blo(av.w) * (blo(b0.w) + blo(b1.w)) + bhi(av.w) * (bhi(b0.w) + bhi(b1.w));
  }
  if (j < end) {
    int u0 = csr[j];
    uint4 b0 = *(const uint4*)(anb + (size_t)u0 * 64 + lane * 8);
    acc += blo(av.x) * blo(b0.x) + bhi(av.x) * bhi(b0.x)
         + blo(av.y) * blo(b0.y) + bhi(av.y) * bhi(b0.y)
         + blo(av.z) * blo(b0.z) + bhi(av.z) * bhi(b0.z)
         + blo(av.w) * blo(b0.w) + bhi(av.w) * bhi(b0.w);
  }
  acc += __shfl_xor(acc, 1); acc += __shfl_xor(acc, 2); acc += __shfl_xor(acc, 4);
  if (lane == 0) {
    float m = (1.0f + acc) / (float)(end - beg + 1);  // self-loop dot = 1
    out[g] = 1.0f / (1.0f + expf(-temp[0] * m));
  }
}

// ---------------- SAGE mean aggregation (bf16 in/out, f32 accumulate) ----------------

__global__ void agg_b_kernel(const ushort* __restrict__ h, const int* __restrict__ rowptr,
                             const int* __restrict__ csr, ushort* __restrict__ outb, int n) {
  int g = (blockIdx.x * blockDim.x + threadIdx.x) >> 4;  // 16 lanes / node
  int lane = threadIdx.x & 15;
  if (g >= n) return;
  int beg = rowptr[g], end = rowptr[g + 1];
  float a0=0,a1=0,a2=0,a3=0,a4=0,a5=0,a6=0,a7=0;
  int j = beg;
  for (; j + 3 < end; j += 4) {
    int u0 = csr[j], u1 = csr[j + 1], u2 = csr[j + 2], u3 = csr[j + 3];
    uint4 v0 = *(const uint4*)(h + (size_t)u0 * HID + lane * 8);
    uint4 v1 = *(const uint4*)(h + (size_t)u1 * HID + lane * 8);
    uint4 v2 = *(const uint4*)(h + (size_t)u2 * HID + lane * 8);
    uint4 v3 = *(const uint4*)(h + (size_t)u3 * HID + lane * 8);
    a0 += (blo(v0.x) + blo(v1.x)) + (blo(v2.x) + blo(v3.x));
    a1 += (bhi(v0.x) + bhi(v1.x)) + (bhi(v2.x) + bhi(v3.x));
    a2 += (blo(v0.y) + blo(v1.y)) + (blo(v2.y) + blo(v3.y));
    a3 += (bhi(v0.y) + bhi(v1.y)) + (bhi(v2.y) + bhi(v3.y));
    a4 += (blo(v0.z) + blo(v1.z)) + (blo(v2.z) + blo(v3.z));
    a5 += (bhi(v0.z) + bhi(v1.z)) + (bhi(v2.z) + bhi(v3.z));
    a6 += (blo(v0.w) + blo(v1.w)) + (blo(v2.w) + blo(v3.w));
    a7 += (bhi(v0.w) + bhi(v1.w)) + (bhi(v2.w) + bhi(v3.w));
  }
  for (; j < end; ++j) {
    int u0 = csr[j];
    uint4 v0 = *(const uint4*)(h + (size_t)u0 * HID + lane * 8);
    a0 += blo(v0.x); a1 += bhi(v0.x); a2 += blo(v0.y); a3 += bhi(v0.y);
    a4 += blo(v0.z); a5 += bhi(v0.z); a6 += blo(v0.w); a7 += bhi(v0.w);
  }
  float r = (end > beg) ? 1.0f / (float)(end - beg) : 0.0f;
  uint4 o;
  o.x = pack2(a0 * r, a1 * r); o.y = pack2(a2 * r, a3 * r);
  o.z = pack2(a4 * r, a5 * r); o.w = pack2(a6 * r, a7 * r);
  *(uint4*)(outb + (size_t)g * HID + lane * 8) = o;
}

// ---------------- MFMA linear: C = A1@W1^T (+ A2@W2^T) + bias, bf16 in, bf16 out ----

template <int NPARTS, bool STATS, bool ORELU>
__global__ __launch_bounds__(256) void mlin_kernel(
    const ushort* __restrict__ A1, const ushort* __restrict__ A2, int K,
    const ushort* __restrict__ W1, const ushort* __restrict__ W2,
    const float* __restrict__ bias, ushort* __restrict__ C,
    float* __restrict__ stats, int M) {
  __shared__ ushort As[128 * 32];
  __shared__ ushort Bs[128 * 32];
  const int tid = threadIdx.x;
  const int w = tid >> 6, l = tid & 63;
  const int mbase = blockIdx.x * 128;
  const int lm = l & 15, lq = l >> 4;
  floatx4 acc[2][8];
#pragma unroll
  for (int mt = 0; mt < 2; ++mt)
#pragma unroll
    for (int nt = 0; nt < 8; ++nt) {
      floatx4 z = {0.f, 0.f, 0.f, 0.f};
      acc[mt][nt] = z;
    }

  for (int part = 0; part < NPARTS; ++part) {
    const ushort* Ap = part ? A2 : A1;
    const ushort* Wp = part ? W2 : W1;
    for (int k0 = 0; k0 < K; k0 += 32) {
#pragma unroll
      for (int i = 0; i < 2; ++i) {
        int s = w * 2 + i;
        int rt = s * 16 + (l >> 2);
        int q = (l & 3) ^ ((rt >> 1) & 3);
        int grow = mbase + rt; grow = grow < M ? grow : M - 1;
        async_cp16(Ap + (size_t)grow * K + k0 + q * 8, &As[s * 512]);
        async_cp16(Wp + (size_t)rt * K + k0 + q * 8, &Bs[s * 512]);
      }
      __syncthreads();
      short8 b[8];
#pragma unroll
      for (int nt = 0; nt < 8; ++nt) {
        int row = nt * 16 + lm;
        int q = lq ^ ((row >> 1) & 3);
        b[nt] = *(const short8*)&Bs[row * 32 + q * 8];
      }
#pragma unroll
      for (int mt = 0; mt < 2; ++mt) {
        int row = (w * 2 + mt) * 16 + lm;
        int q = lq ^ ((row >> 1) & 3);
        short8 a = *(const short8*)&As[row * 32 + q * 8];
#pragma unroll
        for (int nt = 0; nt < 8; ++nt)
          acc[mt][nt] = __builtin_amdgcn_mfma_f32_16x16x32_bf16(a, b[nt], acc[mt][nt], 0, 0, 0);
      }
      __syncthreads();
    }
  }

  // epilogue: C/D layout col = lane&15, row = (lane>>4)*4 + reg
  float ss[8], qq[8];
#pragma unroll
  for (int nt = 0; nt < 8; ++nt) { ss[nt] = 0.f; qq[nt] = 0.f; }
#pragma unroll
  for (int nt = 0; nt < 8; ++nt) {
    int col = nt * 16 + lm;
    float bv = bias[col];
#pragma unroll
    for (int mt = 0; mt < 2; ++mt) {
      int rbase = mbase + (w * 2 + mt) * 16 + lq * 4;
#pragma unroll
      for (int r = 0; r < 4; ++r) {
        int grow = rbase + r;
        if (grow < M) {
          float val = acc[mt][nt][r] + bv;
          if (ORELU) val = fmaxf(val, 0.f);
          C[(size_t)grow * 128 + col] = f2b(val);
          if (STATS) { ss[nt] += val; qq[nt] += val * val; }
        }
      }
    }
  }
  if (STATS) {
    float* sred = (float*)As;  // safe: past last barrier, no more tile reads
    if (tid < 256) sred[tid] = 0.f;
    __syncthreads();
#pragma unroll
    for (int nt = 0; nt < 8; ++nt) {
      ss[nt] += __shfl_xor(ss[nt], 16); ss[nt] += __shfl_xor(ss[nt], 32);
      qq[nt] += __shfl_xor(qq[nt], 16); qq[nt] += __shfl_xor(qq[nt], 32);
    }
    if (lq == 0) {
#pragma unroll
      for (int nt = 0; nt < 8; ++nt) {
        int col = nt * 16 + lm;
        atomicAdd(&sred[col], ss[nt]);
        atomicAdd(&sred[128 + col], qq[nt]);
      }
    }
    __syncthreads();
    if (tid < 256) atomicAdd(&stats[tid], sred[tid]);
  }
}

// ---------------- BatchNorm apply (bf16 in-place, latency-optimized) ----------------

template <int ACT>  // 0=relu, 1=sigmoid
__global__ __launch_bounds__(256) void bnb_kernel(
    ushort* __restrict__ buf, const float* __restrict__ stats,
    const float* __restrict__ gamma, const float* __restrict__ beta, int n) {
  const int S = gridDim.x * 256;  // multiple of 16
  int idx = blockIdx.x * 256 + threadIdx.x;
  const int c0 = (idx & 15) * 8;
  const float inv_n = 1.0f / (float)n;
  float sc[8], sh[8];
#pragma unroll
  for (int d = 0; d < 8; ++d) {
    int c = c0 + d;
    float mu = stats[c] * inv_n;
    float var = stats[128 + c] * inv_n - mu * mu;
    float s = rsqrtf(var + 1e-5f) * gamma[c];
    sc[d] = s;
    sh[d] = beta[c] - mu * s;
  }
  const int n16 = n * 16;
  for (; idx < n16; idx += S) {
    uint4 v = ((const uint4*)buf)[idx];
    float x[8] = {blo(v.x), bhi(v.x), blo(v.y), bhi(v.y),
                  blo(v.z), bhi(v.z), blo(v.w), bhi(v.w)};
#pragma unroll
    for (int d = 0; d < 8; ++d) {
      float y = x[d] * sc[d] + sh[d];
      x[d] = (ACT == 0) ? fmaxf(y, 0.f) : 1.0f / (1.0f + expf(-y));
    }
    uint4 o;
    o.x = pack2(x[0], x[1]); o.y = pack2(x[2], x[3]);
    o.z = pack2(x[4], x[5]); o.w = pack2(x[6], x[7]);
    ((uint4*)buf)[idx] = o;
  }
}

// ---------------- classifier: MFMA GEMM + fused log_softmax ----------------
// Inputs Hg/Hp already relu'd by their producers. Wcb: 48x256 bf16 (rows 40+ zero).
// acc layout: row = mbase + (w*2+mt)*16 + lq*4 + r, col = nt*16 + lm. For fixed
// (mt,r) the 16 lanes {lq*16+lm} hold all 48 cols of one row -> shfl_xor reduce.

__global__ __launch_bounds__(256) void clsm_kernel(
    const ushort* __restrict__ A1, const ushort* __restrict__ A2,
    const ushort* __restrict__ Wcb, const float* __restrict__ bias,
    float* __restrict__ C, int M) {
  __shared__ ushort As[128 * 32];
  __shared__ ushort Bs[48 * 32];
  const int tid = threadIdx.x;
  const int w = tid >> 6, l = tid & 63;
  const int mbase = blockIdx.x * 128;
  const int lm = l & 15, lq = l >> 4;
  floatx4 acc[2][3];
#pragma unroll
  for (int mt = 0; mt < 2; ++mt)
#pragma unroll
    for (int nt = 0; nt < 3; ++nt) {
      floatx4 z = {0.f, 0.f, 0.f, 0.f};
      acc[mt][nt] = z;
    }

  for (int part = 0; part < 2; ++part) {
    const ushort* Ap = part ? A2 : A1;
    for (int k0 = 0; k0 < 128; k0 += 32) {
#pragma unroll
      for (int i = 0; i < 2; ++i) {
        int s = w * 2 + i;
        int rt = s * 16 + (l >> 2);
        int q = (l & 3) ^ ((rt >> 1) & 3);
        int grow = mbase + rt; grow = grow < M ? grow : M - 1;
        async_cp16(Ap + (size_t)grow * 128 + k0 + q * 8, &As[s * 512]);
      }
      if (w < 3) {
        int rt = w * 16 + (l >> 2);
        int q = (l & 3) ^ ((rt >> 1) & 3);
        async_cp16(Wcb + (size_t)rt * 256 + part * 128 + k0 + q * 8, &Bs[w * 512]);
      }
      __syncthreads();
      short8 b[3];
#pragma unroll
      for (int nt = 0; nt < 3; ++nt) {
        int row = nt * 16 + lm;
        int q = lq ^ ((row >> 1) & 3);
        b[nt] = *(const short8*)&Bs[row * 32 + q * 8];
      }
#pragma unroll
      for (int mt = 0; mt < 2; ++mt) {
        int row = (w * 2 + mt) * 16 + lm;
        int q = lq ^ ((row >> 1) & 3);
        short8 a = *(const short8*)&As[row * 32 + q * 8];
#pragma unroll
        for (int nt = 0; nt < 3; ++nt)
          acc[mt][nt] = __builtin_amdgcn_mfma_f32_16x16x32_bf16(a, b[nt], acc[mt][nt], 0, 0, 0);
      }
      __syncthreads();
    }
  }

  float b0v = bias[lm], b1v = bias[lm + 16];
  float b2v = (lm < 8) ? bias[lm + 32] : 0.f;
#pragma unroll
  for (int mt = 0; mt < 2; ++mt) {
#pragma unroll
    for (int r = 0; r < 4; ++r) {
      int grow = mbase + (w * 2 + mt) * 16 + lq * 4 + r;
      float v0 = acc[mt][0][r] + b0v;
      float v1 = acc[mt][1][r] + b1v;
      float v2 = (lm < 8) ? acc[mt][2][r] + b2v : -3.4e38f;
      float m = fmaxf(fmaxf(v0, v1), v2);
      m = fmaxf(m, __shfl_xor(m, 1)); m = fmaxf(m, __shfl_xor(m, 2));
      m = fmaxf(m, __shfl_xor(m, 4)); m = fmaxf(m, __shfl_xor(m, 8));
      float s = expf(v0 - m) + expf(v1 - m) + ((lm < 8) ? expf(v2 - m) : 0.f);
      s += __shfl_xor(s, 1); s += __shfl_xor(s, 2);
      s += __shfl_xor(s, 4); s += __shfl_xor(s, 8);
      float ls = m + logf(s);
      if (grow < M) {
        C[(size_t)grow * OUTC + lm] = v0 - ls;
        C[(size_t)grow * OUTC + lm + 16] = v1 - ls;
        if (lm < 8) C[(size_t)grow * OUTC + lm + 32] = v2 - ls;
      }
    }
  }
}

// ---------------- launch ----------------

extern "C" void kernel_launch(void* const* d_in, const int* in_sizes, int n_in,
                              void* d_out, int out_size, void* d_ws, size_t ws_size,
                              hipStream_t stream) {
  const float* x       = (const float*)d_in[0];
  const float* alpha   = (const float*)d_in[1];
  const int*   eidx    = (const int*)d_in[2];
  const float* sage_Wl = (const float*)d_in[3];
  const float* sage_bl = (const float*)d_in[4];
  const float* sage_Wr = (const float*)d_in[5];
  const float* sage_g  = (const float*)d_in[6];
  const float* sage_b  = (const float*)d_in[7];
  const float* W0 = (const float*)d_in[8];
  const float* b0 = (const float*)d_in[9];
  const float* W1 = (const float*)d_in[10];
  const float* b1 = (const float*)d_in[11];
  const float* W2 = (const float*)d_in[12];
  const float* b2 = (const float*)d_in[13];
  const float* mg = (const float*)d_in[14];
  const float* mb = (const float*)d_in[15];
  const float* Wc = (const float*)d_in[16];
  const float* bc = (const float*)d_in[17];
  const float* temp = (const float*)d_in[18];
  float* out = (float*)d_out;

  const int n = in_sizes[0] / HID;  // 100000
  const int e = in_sizes[2] / 2;    // 1600000
  const int* src = eidx;
  const int* tgt = eidx + e;

  const int nbk = (n + 511) >> 9;
  const int glen = nbk * PB;
  const int chunk = (e + PB - 1) / PB;

  // workspace layout (bf16 buffers first: 16B aligned)
  char* p = (char*)d_ws;
  ushort* xb     = (ushort*)p; p += (size_t)n * HID * 2;   // alias: hgnn
  ushort* hb     = (ushort*)p; p += (size_t)n * HID * 2;   // alias: anb
  ushort* aggb   = (ushort*)p; p += (size_t)n * HID * 2;   // alias: ab
  ushort* hproto = (ushort*)p; p += (size_t)n * HID * 2;   // alias: ebuf
  ushort* wb     = (ushort*)p; p += (size_t)WTOT * 2;
  ushort* wcb    = (ushort*)p; p += (size_t)48 * 256 * 2;
  float* stats = (float*)p; p += 1024 * 4;
  int* rowptr = (int*)p; p += ((size_t)n + 1) * 4;
  int* csr    = (int*)p; p += (size_t)e * 4;
  int* G      = (int*)p; p += (size_t)glen * 4;
  int* Gs     = (int*)p; p += (size_t)glen * 4;
  int* blks   = (int*)p;
  ushort* ab   = aggb;
  ushort* hgnn = xb;
  ushort* anb  = hb;
  int*    ebuf = (int*)hproto;
  ushort* Wlb = wb, *Wrb = wb + 49152, *W0b = wb + 98304, *W1b = wb + 106496, *W2b = wb + 122880;

  const int T = 256;
  const int nb_scan = (glen + SCAN_ELEMS - 1) / SCAN_ELEMS;

  // ---- init + converts ----
  init_kernel<<<4, T, 0, stream>>>(stats);
  cvt_kernel<<<(n * (HID / 4) + T - 1) / T, T, 0, stream>>>(x, xb, n * (HID / 4));
  cvt_kernel<<<(n * 16 + T - 1) / T, T, 0, stream>>>(alpha, ab, n * 16);
  cvtw_kernel<<<(WTOT / 4 + T - 1) / T, T, 0, stream>>>(sage_Wl, sage_Wr, W0, W1, W2, wb);
  cvtwc_kernel<<<12, T, 0, stream>>>(Wc, wcb);
  anorm_kernel<<<(int)(((size_t)n * 16 + T - 1) / T), T, 0, stream>>>(alpha, anb, n);

  // ---- bucketed CSR build ----
  binA_kernel<<<PB, T, 0, stream>>>(tgt, G, e, chunk, nbk);
  scan1_kernel<<<nb_scan, SCAN_T, 0, stream>>>(G, Gs, blks, glen);
  scan2_kernel<<<1, SCAN_T, 0, stream>>>(blks, nb_scan);
  scan3g_kernel<<<(glen + T - 1) / T, T, 0, stream>>>(Gs, blks, glen);
  binB_kernel<<<PB, T, 0, stream>>>(src, tgt, Gs, ebuf, e, chunk, nbk);
  binC_kernel<<<nbk, T, 0, stream>>>(ebuf, Gs, rowptr, csr, n, e, nbk);

  // ---- gate (pull, fused sigmoid) ----
  gate_pull_kernel<<<(int)(((size_t)n * 8 + T - 1) / T), T, 0, stream>>>(
      anb, rowptr, csr, temp, out + (size_t)n * OUTC, n);

  const int gLin = (n + 127) / 128;
  const int gElem = (n * 16 + T - 1) / T;
  const int gBn = 1024;

  // ---- Proto MLP (hb free after gate_pull consumed anb) ----
  mlin_kernel<1, true, false><<<gLin, T, 0, stream>>>(ab, nullptr, 64, W0b, nullptr, b0, hb, stats + 512, n);
  bnb_kernel<1><<<gBn, T, 0, stream>>>(hb, stats + 512, mg, mb, n);
  mlin_kernel<1, true, false><<<gLin, T, 0, stream>>>(hb, nullptr, 128, W1b, nullptr, b1, hb, stats + 768, n);
  bnb_kernel<1><<<gBn, T, 0, stream>>>(hb, stats + 768, mg + HID, mb + HID, n);
  mlin_kernel<1, false, true><<<gLin, T, 0, stream>>>(hb, nullptr, 128, W2b, nullptr, b2, hproto, nullptr, n);

  // ---- SAGE ----
  agg_b_kernel<<<gElem, T, 0, stream>>>(xb, rowptr, csr, aggb, n);
  mlin_kernel<2, true, false><<<gLin, T, 0, stream>>>(aggb, xb, 128, Wlb, Wrb, sage_bl, hb, stats + 0, n);
  bnb_kernel<0><<<gBn, T, 0, stream>>>(hb, stats + 0, sage_g, sage_b, n);
  agg_b_kernel<<<gElem, T, 0, stream>>>(hb, rowptr, csr, aggb, n);
  mlin_kernel<2, true, false><<<gLin, T, 0, stream>>>(aggb, hb, 128, Wlb + 16384, Wrb + 16384,
                                                      sage_bl + HID, hb, stats + 256, n);
  bnb_kernel<0><<<gBn, T, 0, stream>>>(hb, stats + 256, sage_g + HID, sage_b + HID, n);
  agg_b_kernel<<<gElem, T, 0, stream>>>(hb, rowptr, csr, aggb, n);
  mlin_kernel<2, false, true><<<gLin, T, 0, stream>>>(aggb, hb, 128, Wlb + 32768, Wrb + 32768,
                                                      sage_bl + 2 * HID, hgnn, nullptr, n);

  // ---- classifier (MFMA, log_softmax fused) ----
  clsm_kernel<<<gLin, T, 0, stream>>>(hgnn, hproto, wcb, bc, out, n);
}